// Round 1
// baseline (620.442 us; speedup 1.0000x reference)
//
#include <hip/hip_runtime.h>

#define D 128
#define LN_EPS 1e-5f

// ---------------------------------------------------------------------------
// LayerNorm + Linear (128 -> 128). One block of 128 threads per row.
// Handles the 7D->4D transpose via index math:
//   row = l*perL + j,  l = X*8+Y,  j = n*w1w2 + w1*w2d + w2
//   input offset = ((((n*8+X)*8+Y)*8+w1)*w2d + w2) * 128
// Output layout: [row][128] contiguous (l-major, j-minor).
// ---------------------------------------------------------------------------
__global__ void ln_linear_kernel(const float* __restrict__ in,
                                 const float* __restrict__ g,
                                 const float* __restrict__ bvec,
                                 const float* __restrict__ W,
                                 const float* __restrict__ bias,
                                 float* __restrict__ out,
                                 int perL,   // 384 (q) or 480 (k/v)
                                 int w1w2,   // 64 or 80
                                 int w2d)    // 8 or 10
{
    const int row = blockIdx.x;
    const int tid = threadIdx.x;

    const int l   = row / perL;
    const int j   = row - l * perL;
    const int n   = j / w1w2;
    const int rem = j - n * w1w2;
    const int w1  = rem / w2d;
    const int w2  = rem - w1 * w2d;
    const int X   = l >> 3, Y = l & 7;

    const size_t inoff =
        ((size_t)(((n * 8 + X) * 8 + Y) * 8 + w1) * (size_t)w2d + (size_t)w2) * (size_t)D;

    const float xi = in[inoff + tid];

    __shared__ float xs[D];
    __shared__ float redbuf[2];

    const int wave = tid >> 6;
    const int lane = tid & 63;

    // mean
    float s = xi;
    #pragma unroll
    for (int o = 32; o > 0; o >>= 1) s += __shfl_down(s, o, 64);
    if (lane == 0) redbuf[wave] = s;
    __syncthreads();
    const float mu = (redbuf[0] + redbuf[1]) * (1.0f / 128.0f);
    __syncthreads();   // protect redbuf before reuse

    // variance
    const float dx = xi - mu;
    float vs = dx * dx;
    #pragma unroll
    for (int o = 32; o > 0; o >>= 1) vs += __shfl_down(vs, o, 64);
    if (lane == 0) redbuf[wave] = vs;
    __syncthreads();
    const float var  = (redbuf[0] + redbuf[1]) * (1.0f / 128.0f);
    const float rstd = rsqrtf(var + LN_EPS);

    xs[tid] = dx * rstd * g[tid] + bvec[tid];
    __syncthreads();

    // xn @ W + bias : thread tid computes output column tid.
    // W is [in=128][out=128]; W[i*128+tid] is coalesced across threads.
    float acc = bias[tid];
    #pragma unroll 8
    for (int i = 0; i < D; ++i) acc += xs[i] * W[i * D + tid];

    out[(size_t)row * D + tid] = acc;
}

// ---------------------------------------------------------------------------
// Attention: one block per (l, head). 384 threads = one query each.
// Online softmax over 480 keys, dh=32 held in 8 float4 registers.
// K/V rows are read with uniform address across the wave -> L1 broadcast.
// ---------------------------------------------------------------------------
__global__ void attn_kernel(const float* __restrict__ qp,
                            const float* __restrict__ kp,
                            const float* __restrict__ vp,
                            const float* __restrict__ attn_scale,
                            float* __restrict__ out)
{
    const int l = blockIdx.x;   // 0..63
    const int h = blockIdx.y;   // 0..3
    const int q = threadIdx.x;  // 0..383

    const float scale = attn_scale[0] * 0.17677669529663687f; // * dh^-0.5

    const float4* qrow = (const float4*)(qp + ((size_t)l * 384 + q) * D + h * 32);
    float4 qv[8];
    #pragma unroll
    for (int i = 0; i < 8; ++i) qv[i] = qrow[i];

    float4 o[8];
    #pragma unroll
    for (int i = 0; i < 8; ++i) o[i] = make_float4(0.f, 0.f, 0.f, 0.f);

    float mrun = -1e30f, lrun = 0.f;

    const float* kbase = kp + (size_t)l * 480 * D + h * 32;
    const float* vbase = vp + (size_t)l * 480 * D + h * 32;

    for (int k = 0; k < 480; ++k) {
        const float4* kr = (const float4*)(kbase + (size_t)k * D);
        float s4 = 0.f;
        #pragma unroll
        for (int i = 0; i < 8; ++i) {
            const float4 kv = kr[i];
            s4 += qv[i].x * kv.x + qv[i].y * kv.y + qv[i].z * kv.z + qv[i].w * kv.w;
        }
        const float sc   = s4 * scale;
        const float mnew = fmaxf(mrun, sc);
        const float corr = __expf(mrun - mnew);  // 0 on first iter (exp(-inf))
        const float p    = __expf(sc - mnew);
        lrun = lrun * corr + p;

        const float4* vr = (const float4*)(vbase + (size_t)k * D);
        #pragma unroll
        for (int i = 0; i < 8; ++i) {
            const float4 vv = vr[i];
            o[i].x = o[i].x * corr + p * vv.x;
            o[i].y = o[i].y * corr + p * vv.y;
            o[i].z = o[i].z * corr + p * vv.z;
            o[i].w = o[i].w * corr + p * vv.w;
        }
        mrun = mnew;
    }

    const float inv = 1.0f / lrun;
    float4* orow = (float4*)(out + ((size_t)l * 384 + q) * D + h * 32);
    #pragma unroll
    for (int i = 0; i < 8; ++i) {
        float4 t;
        t.x = o[i].x * inv; t.y = o[i].y * inv;
        t.z = o[i].z * inv; t.w = o[i].w * inv;
        orow[i] = t;
    }
}

// ---------------------------------------------------------------------------
// mean over n (6 views) -> @ Wp + bp -> + skip.
// Uses linearity: mean_n(a_n @ Wp + bp) == (mean_n a_n) @ Wp + bp.
// One block of 128 threads per output row (X,Y,W1,W2); row = l*64 + (W1*8+W2).
// ---------------------------------------------------------------------------
__global__ void proj_kernel(const float* __restrict__ attn,
                            const float* __restrict__ Wp,
                            const float* __restrict__ bp,
                            const float* __restrict__ skip,
                            float* __restrict__ out)
{
    const int row  = blockIdx.x;   // 0..4095
    const int tid  = threadIdx.x;  // 0..127
    const int l    = row >> 6;
    const int qrem = row & 63;

    __shared__ float xs[D];

    float acc = 0.f;
    #pragma unroll
    for (int n = 0; n < 6; ++n)
        acc += attn[((size_t)l * 384 + n * 64 + qrem) * D + tid];
    xs[tid] = acc * (1.0f / 6.0f);
    __syncthreads();

    float r = bp[tid];
    #pragma unroll 8
    for (int i = 0; i < D; ++i) r += xs[i] * Wp[i * D + tid];

    out[(size_t)row * D + tid] = r + skip[(size_t)row * D + tid];
}

// ---------------------------------------------------------------------------
extern "C" void kernel_launch(void* const* d_in, const int* in_sizes, int n_in,
                              void* d_out, int out_size, void* d_ws, size_t ws_size,
                              hipStream_t stream)
{
    const float* q          = (const float*)d_in[0];
    const float* k          = (const float*)d_in[1];
    const float* v          = (const float*)d_in[2];
    const float* skip       = (const float*)d_in[3];
    const float* attn_scale = (const float*)d_in[4];
    const float* lnq_g      = (const float*)d_in[5];
    const float* lnq_b      = (const float*)d_in[6];
    const float* Wq         = (const float*)d_in[7];
    const float* bq         = (const float*)d_in[8];
    const float* lnk_g      = (const float*)d_in[9];
    const float* lnk_b      = (const float*)d_in[10];
    const float* Wk         = (const float*)d_in[11];
    const float* bk         = (const float*)d_in[12];
    const float* lnv_g      = (const float*)d_in[13];
    const float* lnv_b      = (const float*)d_in[14];
    const float* Wv         = (const float*)d_in[15];
    const float* bv         = (const float*)d_in[16];
    const float* Wp         = (const float*)d_in[17];
    const float* bp         = (const float*)d_in[18];

    float* out = (float*)d_out;
    float* ws  = (float*)d_ws;

    // scratch layout (floats): qp | kp | vp | attn
    float* qp   = ws;                               // 64*384*128 = 3,145,728
    float* kp   = qp + (size_t)64 * 384 * 128;      // 64*480*128 = 3,932,160
    float* vp   = kp + (size_t)64 * 480 * 128;
    float* attn = vp + (size_t)64 * 480 * 128;      // 64*384*128

    ln_linear_kernel<<<64 * 384, 128, 0, stream>>>(q, lnq_g, lnq_b, Wq, bq, qp, 384, 64, 8);
    ln_linear_kernel<<<64 * 480, 128, 0, stream>>>(k, lnk_g, lnk_b, Wk, bk, kp, 480, 80, 10);
    ln_linear_kernel<<<64 * 480, 128, 0, stream>>>(v, lnv_g, lnv_b, Wv, bv, vp, 480, 80, 10);

    dim3 agrid(64, 4);
    attn_kernel<<<agrid, 384, 0, stream>>>(qp, kp, vp, attn_scale, attn);

    proj_kernel<<<4096, 128, 0, stream>>>(attn, Wp, bp, skip, out);
}

// Round 2
// 537.562 us; speedup vs baseline: 1.1542x; 1.1542x over previous
//
#include <hip/hip_runtime.h>

#define D 128
#define LN_EPS 1e-5f
#define RPB 16          // rows per block in GEMM kernels
#define XSTR 20         // padded LDS stride (floats) for transposed xn tile

// ---------------------------------------------------------------------------
// LayerNorm + Linear (128 -> 128), 16 rows per block, 128 threads.
// Phase A: each thread loads element `tid` of 16 rows, two-wave reduction for
//          mean/var (single pass: sum, sumsq), stores normalized rows
//          TRANSPOSED into LDS xs_t[i][r] (stride 20: 16B-aligned, bank-safe).
// Phase B: 4x4 register micro-tile GEMM: thread (rg,cg) computes rows
//          rg*4..+3 x cols cg*4..+3. Inner loop: 1 ds_read_b128 (4 rows at
//          elem i) + 1 float4 W load + 16 FMA.
// ---------------------------------------------------------------------------
__global__ __launch_bounds__(128)
void ln_linear_kernel(const float* __restrict__ in,
                      const float* __restrict__ g,
                      const float* __restrict__ bvec,
                      const float* __restrict__ W,
                      const float* __restrict__ bias,
                      float* __restrict__ out,
                      int perL,   // 384 (q) or 480 (k/v)
                      int w1w2,   // 64 or 80
                      int w2d)    // 8 or 10
{
    const int tid  = threadIdx.x;
    const int wave = tid >> 6;
    const int lane = tid & 63;
    const int base = blockIdx.x * RPB;

    __shared__ float xs_t[128 * XSTR];
    __shared__ float red1[2][RPB];
    __shared__ float red2[2][RPB];

    // ---- Phase A: load 16 rows (element tid of each) ----
    float xv[RPB];
    #pragma unroll
    for (int r = 0; r < RPB; ++r) {
        const int row = base + r;
        const int l   = row / perL;
        const int j   = row - l * perL;
        const int n   = j / w1w2;
        const int rem = j - n * w1w2;
        const int w1  = rem / w2d;
        const int w2  = rem - w1 * w2d;
        const int X   = l >> 3, Y = l & 7;
        const size_t inoff =
            ((size_t)(((n * 8 + X) * 8 + Y) * 8 + w1) * (size_t)w2d + (size_t)w2) * (size_t)D;
        xv[r] = in[inoff + tid];
    }

    #pragma unroll
    for (int r = 0; r < RPB; ++r) {
        float s1 = xv[r];
        float s2 = xv[r] * xv[r];
        #pragma unroll
        for (int o = 32; o > 0; o >>= 1) {
            s1 += __shfl_down(s1, o, 64);
            s2 += __shfl_down(s2, o, 64);
        }
        if (lane == 0) { red1[wave][r] = s1; red2[wave][r] = s2; }
    }
    __syncthreads();

    const float gt = g[tid], bt = bvec[tid];
    float xn[RPB];
    #pragma unroll
    for (int r = 0; r < RPB; ++r) {
        const float mu  = (red1[0][r] + red1[1][r]) * (1.0f / 128.0f);
        const float ms  = (red2[0][r] + red2[1][r]) * (1.0f / 128.0f);
        const float var = ms - mu * mu;
        const float rstd = rsqrtf(var + LN_EPS);
        xn[r] = (xv[r] - mu) * rstd * gt + bt;
    }
    // transposed store: xs_t[tid*XSTR + r], as 4x ds_write_b128
    #pragma unroll
    for (int j = 0; j < 4; ++j) {
        *(float4*)(&xs_t[tid * XSTR + j * 4]) =
            make_float4(xn[j * 4 + 0], xn[j * 4 + 1], xn[j * 4 + 2], xn[j * 4 + 3]);
    }
    __syncthreads();

    // ---- Phase B: 4x4 micro-tile GEMM ----
    const int cg = tid & 31;   // cols cg*4..+3
    const int rg = tid >> 5;   // rows rg*4..+3

    const float4 b4 = ((const float4*)bias)[cg];
    float4 a0 = b4, a1 = b4, a2 = b4, a3 = b4;

    const float4* Wv = (const float4*)W;   // Wv[i*32 + cg]
    #pragma unroll 4
    for (int i = 0; i < D; ++i) {
        const float4 w  = Wv[i * 32 + cg];
        const float4 xr = *(const float4*)(&xs_t[i * XSTR + rg * 4]);
        a0.x += w.x * xr.x; a0.y += w.y * xr.x; a0.z += w.z * xr.x; a0.w += w.w * xr.x;
        a1.x += w.x * xr.y; a1.y += w.y * xr.y; a1.z += w.z * xr.y; a1.w += w.w * xr.y;
        a2.x += w.x * xr.z; a2.y += w.y * xr.z; a2.z += w.z * xr.z; a2.w += w.w * xr.z;
        a3.x += w.x * xr.w; a3.y += w.y * xr.w; a3.z += w.z * xr.w; a3.w += w.w * xr.w;
    }

    float4* outv = (float4*)out;
    const int r0 = base + rg * 4;
    outv[(size_t)(r0 + 0) * 32 + cg] = a0;
    outv[(size_t)(r0 + 1) * 32 + cg] = a1;
    outv[(size_t)(r0 + 2) * 32 + cg] = a2;
    outv[(size_t)(r0 + 3) * 32 + cg] = a3;
}

// ---------------------------------------------------------------------------
// Attention, quad-split: 4 threads per query, each owns 8 of the 32 dh
// elements. Block = 256 threads = 64 queries; grid (6 qblocks, 64 l, 4 h).
// Partial dot combined with 2 shfl_xor hops inside the quad; online softmax
// state (m, l) replicated across the quad.
// ---------------------------------------------------------------------------
__global__ __launch_bounds__(256)
void attn_kernel(const float* __restrict__ qp,
                 const float* __restrict__ kp,
                 const float* __restrict__ vp,
                 const float* __restrict__ attn_scale,
                 float* __restrict__ out)
{
    const int qb = blockIdx.x;            // 0..5
    const int l  = blockIdx.y;            // 0..63
    const int h  = blockIdx.z;            // 0..3
    const int q    = qb * 64 + (threadIdx.x >> 2);
    const int part = threadIdx.x & 3;     // which 8 of 32 dh elems

    const float scale = attn_scale[0] * 0.17677669529663687f; // * dh^-0.5

    const float4* qrow =
        (const float4*)(qp + ((size_t)l * 384 + q) * D + h * 32 + part * 8);
    const float4 qv0 = qrow[0];
    const float4 qv1 = qrow[1];

    float4 o0 = make_float4(0.f, 0.f, 0.f, 0.f);
    float4 o1 = make_float4(0.f, 0.f, 0.f, 0.f);
    float mrun = -1e30f, lrun = 0.f;

    const float* kbase = kp + (size_t)l * 480 * D + h * 32 + part * 8;
    const float* vbase = vp + (size_t)l * 480 * D + h * 32 + part * 8;

    for (int k = 0; k < 480; ++k) {
        const float4* kr = (const float4*)(kbase + (size_t)k * D);
        const float4 k0 = kr[0];
        const float4 k1 = kr[1];
        float s = qv0.x * k0.x + qv0.y * k0.y + qv0.z * k0.z + qv0.w * k0.w
                + qv1.x * k1.x + qv1.y * k1.y + qv1.z * k1.z + qv1.w * k1.w;
        // combine 4 partials within the quad
        s += __shfl_xor(s, 1, 64);
        s += __shfl_xor(s, 2, 64);

        const float sc   = s * scale;
        const float mnew = fmaxf(mrun, sc);
        const float corr = __expf(mrun - mnew);   // ==0 on first iter
        const float p    = __expf(sc - mnew);
        lrun = lrun * corr + p;

        const float4* vr = (const float4*)(vbase + (size_t)k * D);
        const float4 v0 = vr[0];
        const float4 v1 = vr[1];
        o0.x = o0.x * corr + p * v0.x; o0.y = o0.y * corr + p * v0.y;
        o0.z = o0.z * corr + p * v0.z; o0.w = o0.w * corr + p * v0.w;
        o1.x = o1.x * corr + p * v1.x; o1.y = o1.y * corr + p * v1.y;
        o1.z = o1.z * corr + p * v1.z; o1.w = o1.w * corr + p * v1.w;
        mrun = mnew;
    }

    const float inv = 1.0f / lrun;
    float4* orow = (float4*)(out + ((size_t)l * 384 + q) * D + h * 32 + part * 8);
    orow[0] = make_float4(o0.x * inv, o0.y * inv, o0.z * inv, o0.w * inv);
    orow[1] = make_float4(o1.x * inv, o1.y * inv, o1.z * inv, o1.w * inv);
}

// ---------------------------------------------------------------------------
// mean over n (6 views) -> @ Wp + bp -> + skip. Same 16-row / 4x4 micro-tile
// structure as ln_linear (no LN, mean instead).
// ---------------------------------------------------------------------------
__global__ __launch_bounds__(128)
void proj_kernel(const float* __restrict__ attn,
                 const float* __restrict__ Wp,
                 const float* __restrict__ bp,
                 const float* __restrict__ skip,
                 float* __restrict__ out)
{
    const int tid  = threadIdx.x;
    const int base = blockIdx.x * RPB;

    __shared__ float xs_t[128 * XSTR];

    float xn[RPB];
    #pragma unroll
    for (int r = 0; r < RPB; ++r) {
        const int row  = base + r;
        const int l    = row >> 6;
        const int qrem = row & 63;
        float acc = 0.f;
        #pragma unroll
        for (int n = 0; n < 6; ++n)
            acc += attn[((size_t)l * 384 + n * 64 + qrem) * D + tid];
        xn[r] = acc * (1.0f / 6.0f);
    }
    #pragma unroll
    for (int j = 0; j < 4; ++j) {
        *(float4*)(&xs_t[tid * XSTR + j * 4]) =
            make_float4(xn[j * 4 + 0], xn[j * 4 + 1], xn[j * 4 + 2], xn[j * 4 + 3]);
    }
    __syncthreads();

    const int cg = tid & 31;
    const int rg = tid >> 5;

    const float4 b4 = ((const float4*)bp)[cg];
    float4 a0 = b4, a1 = b4, a2 = b4, a3 = b4;

    const float4* Wv = (const float4*)Wp;
    #pragma unroll 4
    for (int i = 0; i < D; ++i) {
        const float4 w  = Wv[i * 32 + cg];
        const float4 xr = *(const float4*)(&xs_t[i * XSTR + rg * 4]);
        a0.x += w.x * xr.x; a0.y += w.y * xr.x; a0.z += w.z * xr.x; a0.w += w.w * xr.x;
        a1.x += w.x * xr.y; a1.y += w.y * xr.y; a1.z += w.z * xr.y; a1.w += w.w * xr.y;
        a2.x += w.x * xr.z; a2.y += w.y * xr.z; a2.z += w.z * xr.z; a2.w += w.w * xr.z;
        a3.x += w.x * xr.w; a3.y += w.y * xr.w; a3.z += w.z * xr.w; a3.w += w.w * xr.w;
    }

    const float4* skv = (const float4*)skip;
    float4* outv = (float4*)out;
    const int r0 = base + rg * 4;
    #pragma unroll
    for (int k = 0; k < 4; ++k) {
        float4 a = (k == 0) ? a0 : (k == 1) ? a1 : (k == 2) ? a2 : a3;
        const float4 sk = skv[(size_t)(r0 + k) * 32 + cg];
        outv[(size_t)(r0 + k) * 32 + cg] =
            make_float4(a.x + sk.x, a.y + sk.y, a.z + sk.z, a.w + sk.w);
    }
}

// ---------------------------------------------------------------------------
extern "C" void kernel_launch(void* const* d_in, const int* in_sizes, int n_in,
                              void* d_out, int out_size, void* d_ws, size_t ws_size,
                              hipStream_t stream)
{
    const float* q          = (const float*)d_in[0];
    const float* k          = (const float*)d_in[1];
    const float* v          = (const float*)d_in[2];
    const float* skip       = (const float*)d_in[3];
    const float* attn_scale = (const float*)d_in[4];
    const float* lnq_g      = (const float*)d_in[5];
    const float* lnq_b      = (const float*)d_in[6];
    const float* Wq         = (const float*)d_in[7];
    const float* bq         = (const float*)d_in[8];
    const float* lnk_g      = (const float*)d_in[9];
    const float* lnk_b      = (const float*)d_in[10];
    const float* Wk         = (const float*)d_in[11];
    const float* bk         = (const float*)d_in[12];
    const float* lnv_g      = (const float*)d_in[13];
    const float* lnv_b      = (const float*)d_in[14];
    const float* Wv         = (const float*)d_in[15];
    const float* bv         = (const float*)d_in[16];
    const float* Wp         = (const float*)d_in[17];
    const float* bp         = (const float*)d_in[18];

    float* out = (float*)d_out;
    float* ws  = (float*)d_ws;

    float* qp   = ws;
    float* kp   = qp + (size_t)64 * 384 * 128;
    float* vp   = kp + (size_t)64 * 480 * 128;
    float* attn = vp + (size_t)64 * 480 * 128;

    ln_linear_kernel<<<64 * 384 / RPB, 128, 0, stream>>>(q, lnq_g, lnq_b, Wq, bq, qp, 384, 64, 8);
    ln_linear_kernel<<<64 * 480 / RPB, 128, 0, stream>>>(k, lnk_g, lnk_b, Wk, bk, kp, 480, 80, 10);
    ln_linear_kernel<<<64 * 480 / RPB, 128, 0, stream>>>(v, lnv_g, lnv_b, Wv, bv, vp, 480, 80, 10);

    dim3 agrid(6, 64, 4);
    attn_kernel<<<agrid, 256, 0, stream>>>(qp, kp, vp, attn_scale, attn);

    proj_kernel<<<4096 / RPB, 128, 0, stream>>>(attn, Wp, bp, skip, out);
}

// Round 3
// 286.358 us; speedup vs baseline: 2.1667x; 1.8772x over previous
//
#include <hip/hip_runtime.h>

#define D 128
#define LN_EPS 1e-5f
#define RPB 16          // rows per block in GEMM kernels
#define XSTR 20         // padded LDS stride (floats) for transposed xn tile

#define SSTR 484        // S LDS stride (floats): /4 = 121 odd -> uniform b128 banks
#define VSTR 488        // Vt LDS stride (ushorts): /8 = 61 odd -> uniform b128 banks

typedef __attribute__((ext_vector_type(8))) short short8;
typedef __attribute__((ext_vector_type(4))) float f32x4;

static __device__ __forceinline__ unsigned short f2bf(float f) {
    union { float f; unsigned u; } v; v.f = f;
    unsigned r = v.u + 0x7fffu + ((v.u >> 16) & 1u);   // RTNE
    return (unsigned short)(r >> 16);
}

// ---------------------------------------------------------------------------
// LayerNorm + Linear (128 -> 128), 16 rows/block, 128 threads, bf16 output.
// Optional fold of (attn_scale * dh^-0.5) into the projection (q only).
// ---------------------------------------------------------------------------
__global__ __launch_bounds__(128)
void ln_linear_kernel(const float* __restrict__ in,
                      const float* __restrict__ g,
                      const float* __restrict__ bvec,
                      const float* __restrict__ W,
                      const float* __restrict__ bias,
                      unsigned short* __restrict__ out,   // bf16
                      const float* __restrict__ scale_p,
                      int use_scale,
                      int perL, int w1w2, int w2d)
{
    const int tid  = threadIdx.x;
    const int wave = tid >> 6;
    const int lane = tid & 63;
    const int base = blockIdx.x * RPB;

    __shared__ float xs_t[128 * XSTR];
    __shared__ float red1[2][RPB];
    __shared__ float red2[2][RPB];

    float xv[RPB];
    #pragma unroll
    for (int r = 0; r < RPB; ++r) {
        const int row = base + r;
        const int l   = row / perL;
        const int j   = row - l * perL;
        const int n   = j / w1w2;
        const int rem = j - n * w1w2;
        const int w1  = rem / w2d;
        const int w2  = rem - w1 * w2d;
        const int X   = l >> 3, Y = l & 7;
        const size_t inoff =
            ((size_t)(((n * 8 + X) * 8 + Y) * 8 + w1) * (size_t)w2d + (size_t)w2) * (size_t)D;
        xv[r] = in[inoff + tid];
    }

    #pragma unroll
    for (int r = 0; r < RPB; ++r) {
        float s1 = xv[r];
        float s2 = xv[r] * xv[r];
        #pragma unroll
        for (int o = 32; o > 0; o >>= 1) {
            s1 += __shfl_down(s1, o, 64);
            s2 += __shfl_down(s2, o, 64);
        }
        if (lane == 0) { red1[wave][r] = s1; red2[wave][r] = s2; }
    }
    __syncthreads();

    const float gt = g[tid], bt = bvec[tid];
    float xn[RPB];
    #pragma unroll
    for (int r = 0; r < RPB; ++r) {
        const float mu  = (red1[0][r] + red1[1][r]) * (1.0f / 128.0f);
        const float ms  = (red2[0][r] + red2[1][r]) * (1.0f / 128.0f);
        const float var = ms - mu * mu;
        const float rstd = rsqrtf(var + LN_EPS);
        xn[r] = (xv[r] - mu) * rstd * gt + bt;
    }
    #pragma unroll
    for (int j = 0; j < 4; ++j) {
        *(float4*)(&xs_t[tid * XSTR + j * 4]) =
            make_float4(xn[j * 4 + 0], xn[j * 4 + 1], xn[j * 4 + 2], xn[j * 4 + 3]);
    }
    __syncthreads();

    const int cg = tid & 31;
    const int rg = tid >> 5;

    const float4 b4 = ((const float4*)bias)[cg];
    float4 a0 = b4, a1 = b4, a2 = b4, a3 = b4;

    const float4* Wv = (const float4*)W;
    #pragma unroll 4
    for (int i = 0; i < D; ++i) {
        const float4 w  = Wv[i * 32 + cg];
        const float4 xr = *(const float4*)(&xs_t[i * XSTR + rg * 4]);
        a0.x += w.x * xr.x; a0.y += w.y * xr.x; a0.z += w.z * xr.x; a0.w += w.w * xr.x;
        a1.x += w.x * xr.y; a1.y += w.y * xr.y; a1.z += w.z * xr.y; a1.w += w.w * xr.y;
        a2.x += w.x * xr.z; a2.y += w.y * xr.z; a2.z += w.z * xr.z; a2.w += w.w * xr.z;
        a3.x += w.x * xr.w; a3.y += w.y * xr.w; a3.z += w.z * xr.w; a3.w += w.w * xr.w;
    }

    float s = 1.0f;
    if (use_scale) s = scale_p[0] * 0.17677669529663687f;  // * dh^-0.5
    if (use_scale) {
        a0.x *= s; a0.y *= s; a0.z *= s; a0.w *= s;
        a1.x *= s; a1.y *= s; a1.z *= s; a1.w *= s;
        a2.x *= s; a2.y *= s; a2.z *= s; a2.w *= s;
        a3.x *= s; a3.y *= s; a3.z *= s; a3.w *= s;
    }

    ushort4* outv = (ushort4*)out;
    const int r0 = base + rg * 4;
    outv[(size_t)(r0 + 0) * 32 + cg] = make_ushort4(f2bf(a0.x), f2bf(a0.y), f2bf(a0.z), f2bf(a0.w));
    outv[(size_t)(r0 + 1) * 32 + cg] = make_ushort4(f2bf(a1.x), f2bf(a1.y), f2bf(a1.z), f2bf(a1.w));
    outv[(size_t)(r0 + 2) * 32 + cg] = make_ushort4(f2bf(a2.x), f2bf(a2.y), f2bf(a2.z), f2bf(a2.w));
    outv[(size_t)(r0 + 3) * 32 + cg] = make_ushort4(f2bf(a3.x), f2bf(a3.y), f2bf(a3.z), f2bf(a3.w));
}

// ---------------------------------------------------------------------------
// MFMA attention. One wave per block; block = (l, h, qquad).
// Per q-tile (16 rows):
//   phase 1: S = Q K^T via mfma_f32_16x16x32_bf16 (30 tiles), S -> LDS fp32,
//            row-max tracked in registers (4 shfl_xor once at the end).
//   phase 2: PV with exp fused into the A-frag load (S read b128 -> expf ->
//            bf16 pack -> MFMA vs V^T in LDS). Row sums in-lane; 1/l at end.
// Q was pre-scaled by attn_scale*dh^-0.5 in the projection.
// ---------------------------------------------------------------------------
__global__ __launch_bounds__(64)
void attn_kernel(const unsigned short* __restrict__ qb,
                 const unsigned short* __restrict__ kb,
                 const unsigned short* __restrict__ vb,
                 float* __restrict__ out)
{
    __shared__ float S[16 * SSTR];             // 30,976 B
    __shared__ unsigned short Vt[32 * VSTR];   // 31,232 B
    __shared__ float MROW[16];
    __shared__ float LINV[16];

    const int l  = blockIdx.x;      // 0..63
    const int h  = blockIdx.y;      // 0..3
    const int qq = blockIdx.z;      // 0..3
    const int t  = threadIdx.x;     // 0..63
    const int m16 = t & 15;
    const int g   = t >> 4;

    // ---- stage V^T (32 d x 480 keys, bf16) ----
    {
        const size_t vbase = (size_t)l * 480 * 128 + h * 32;
        const int c4  = (t & 7) * 4;
        const int kof = t >> 3;
        for (int pass = 0; pass < 60; ++pass) {
            const int key = pass * 8 + kof;
            const ushort4 vv = *(const ushort4*)(vb + vbase + (size_t)key * 128 + c4);
            Vt[(c4 + 0) * VSTR + key] = vv.x;
            Vt[(c4 + 1) * VSTR + key] = vv.y;
            Vt[(c4 + 2) * VSTR + key] = vv.z;
            Vt[(c4 + 3) * VSTR + key] = vv.w;
        }
    }
    __syncthreads();

    const short* kq = (const short*)kb;
    const short* qsh = (const short*)qb;

    for (int qt = 0; qt < 6; ++qt) {
        const int qrow0 = qq * 96 + qt * 16;

        // A-frag: Q rows (m = lane&15), k-dim = g*8..+7 (full dh=32)
        const short8 aq = *(const short8*)(
            qsh + ((size_t)(l * 384 + qrow0 + m16)) * 128 + h * 32 + g * 8);

        // ---- phase 1: S tiles + running max ----
        f32x4 vmax = {-1e30f, -1e30f, -1e30f, -1e30f};
        #pragma unroll 6
        for (int kt = 0; kt < 30; ++kt) {
            const short8 bk = *(const short8*)(
                kq + ((size_t)(l * 480 + kt * 16 + m16)) * 128 + h * 32 + g * 8);
            f32x4 z = {0.f, 0.f, 0.f, 0.f};
            f32x4 c = __builtin_amdgcn_mfma_f32_16x16x32_bf16(aq, bk, z, 0, 0, 0);
            const int cb = kt * 16 + m16;
            #pragma unroll
            for (int r = 0; r < 4; ++r) {
                S[(g * 4 + r) * SSTR + cb] = c[r];
                vmax[r] = fmaxf(vmax[r], c[r]);
            }
        }
        #pragma unroll
        for (int off = 1; off < 16; off <<= 1) {
            #pragma unroll
            for (int r = 0; r < 4; ++r)
                vmax[r] = fmaxf(vmax[r], __shfl_xor(vmax[r], off, 64));
        }
        if (m16 == 0) {
            #pragma unroll
            for (int r = 0; r < 4; ++r) MROW[g * 4 + r] = vmax[r];
        }

        // ---- phase 2: PV with fused exp ----
        const float mrow = MROW[m16];
        f32x4 o0 = {0.f, 0.f, 0.f, 0.f};
        f32x4 o1 = {0.f, 0.f, 0.f, 0.f};
        float ssum = 0.f;
        #pragma unroll 3
        for (int kc = 0; kc < 15; ++kc) {
            const f32x4 p0 = *(const f32x4*)&S[m16 * SSTR + kc * 32 + g * 8];
            const f32x4 p1 = *(const f32x4*)&S[m16 * SSTR + kc * 32 + g * 8 + 4];
            float e[8];
            #pragma unroll
            for (int j = 0; j < 4; ++j) {
                e[j]     = __expf(p0[j] - mrow);
                e[4 + j] = __expf(p1[j] - mrow);
            }
            short8 ap;
            #pragma unroll
            for (int j = 0; j < 8; ++j) { ap[j] = (short)f2bf(e[j]); ssum += e[j]; }
            const short8 bv0 = *(const short8*)&Vt[(size_t)m16 * VSTR + kc * 32 + g * 8];
            const short8 bv1 = *(const short8*)&Vt[(size_t)(16 + m16) * VSTR + kc * 32 + g * 8];
            o0 = __builtin_amdgcn_mfma_f32_16x16x32_bf16(ap, bv0, o0, 0, 0, 0);
            o1 = __builtin_amdgcn_mfma_f32_16x16x32_bf16(ap, bv1, o1, 0, 0, 0);
        }
        ssum += __shfl_xor(ssum, 16, 64);
        ssum += __shfl_xor(ssum, 32, 64);
        if (g == 0) LINV[m16] = 1.0f / ssum;

        // ---- epilogue: scale by 1/l, store fp32 ----
        const size_t orow0 = ((size_t)(l * 384 + qrow0)) * 128 + h * 32;
        #pragma unroll
        for (int r = 0; r < 4; ++r) {
            const float inv = LINV[g * 4 + r];
            out[orow0 + (size_t)(g * 4 + r) * 128 + m16]      = o0[r] * inv;
            out[orow0 + (size_t)(g * 4 + r) * 128 + 16 + m16] = o1[r] * inv;
        }
    }
}

// ---------------------------------------------------------------------------
// mean over n (6 views) -> @ Wp + bp -> + skip (fp32 in/out).
// ---------------------------------------------------------------------------
__global__ __launch_bounds__(128)
void proj_kernel(const float* __restrict__ attn,
                 const float* __restrict__ Wp,
                 const float* __restrict__ bp,
                 const float* __restrict__ skip,
                 float* __restrict__ out)
{
    const int tid  = threadIdx.x;
    const int base = blockIdx.x * RPB;

    __shared__ float xs_t[128 * XSTR];

    float xn[RPB];
    #pragma unroll
    for (int r = 0; r < RPB; ++r) {
        const int row  = base + r;
        const int l    = row >> 6;
        const int qrem = row & 63;
        float acc = 0.f;
        #pragma unroll
        for (int n = 0; n < 6; ++n)
            acc += attn[((size_t)l * 384 + n * 64 + qrem) * D + tid];
        xn[r] = acc * (1.0f / 6.0f);
    }
    #pragma unroll
    for (int j = 0; j < 4; ++j) {
        *(float4*)(&xs_t[tid * XSTR + j * 4]) =
            make_float4(xn[j * 4 + 0], xn[j * 4 + 1], xn[j * 4 + 2], xn[j * 4 + 3]);
    }
    __syncthreads();

    const int cg = tid & 31;
    const int rg = tid >> 5;

    const float4 b4 = ((const float4*)bp)[cg];
    float4 a0 = b4, a1 = b4, a2 = b4, a3 = b4;

    const float4* Wv = (const float4*)Wp;
    #pragma unroll 4
    for (int i = 0; i < D; ++i) {
        const float4 w  = Wv[i * 32 + cg];
        const float4 xr = *(const float4*)(&xs_t[i * XSTR + rg * 4]);
        a0.x += w.x * xr.x; a0.y += w.y * xr.x; a0.z += w.z * xr.x; a0.w += w.w * xr.x;
        a1.x += w.x * xr.y; a1.y += w.y * xr.y; a1.z += w.z * xr.y; a1.w += w.w * xr.y;
        a2.x += w.x * xr.z; a2.y += w.y * xr.z; a2.z += w.z * xr.z; a2.w += w.w * xr.z;
        a3.x += w.x * xr.w; a3.y += w.y * xr.w; a3.z += w.z * xr.w; a3.w += w.w * xr.w;
    }

    const float4* skv = (const float4*)skip;
    float4* outv = (float4*)out;
    const int r0 = base + rg * 4;
    #pragma unroll
    for (int k = 0; k < 4; ++k) {
        float4 a = (k == 0) ? a0 : (k == 1) ? a1 : (k == 2) ? a2 : a3;
        const float4 sk = skv[(size_t)(r0 + k) * 32 + cg];
        outv[(size_t)(r0 + k) * 32 + cg] =
            make_float4(a.x + sk.x, a.y + sk.y, a.z + sk.z, a.w + sk.w);
    }
}

// ---------------------------------------------------------------------------
extern "C" void kernel_launch(void* const* d_in, const int* in_sizes, int n_in,
                              void* d_out, int out_size, void* d_ws, size_t ws_size,
                              hipStream_t stream)
{
    const float* q          = (const float*)d_in[0];
    const float* k          = (const float*)d_in[1];
    const float* v          = (const float*)d_in[2];
    const float* skip       = (const float*)d_in[3];
    const float* attn_scale = (const float*)d_in[4];
    const float* lnq_g      = (const float*)d_in[5];
    const float* lnq_b      = (const float*)d_in[6];
    const float* Wq         = (const float*)d_in[7];
    const float* bq         = (const float*)d_in[8];
    const float* lnk_g      = (const float*)d_in[9];
    const float* lnk_b      = (const float*)d_in[10];
    const float* Wk         = (const float*)d_in[11];
    const float* bk         = (const float*)d_in[12];
    const float* lnv_g      = (const float*)d_in[13];
    const float* lnv_b      = (const float*)d_in[14];
    const float* Wv         = (const float*)d_in[15];
    const float* bv         = (const float*)d_in[16];
    const float* Wp         = (const float*)d_in[17];
    const float* bp         = (const float*)d_in[18];

    float* out = (float*)d_out;
    char*  wsb = (char*)d_ws;

    // scratch layout (bytes):
    unsigned short* qb = (unsigned short*)wsb;                       // 6,291,456 B
    unsigned short* kbp = (unsigned short*)(wsb + 6291456);          // 7,864,320 B
    unsigned short* vbp = (unsigned short*)(wsb + 6291456 + 7864320);
    float* attn = (float*)(wsb + 6291456 + 7864320 + 7864320);       // fp32

    ln_linear_kernel<<<64 * 384 / RPB, 128, 0, stream>>>(q, lnq_g, lnq_b, Wq, bq, qb,
                                                         attn_scale, 1, 384, 64, 8);
    ln_linear_kernel<<<64 * 480 / RPB, 128, 0, stream>>>(k, lnk_g, lnk_b, Wk, bk, kbp,
                                                         attn_scale, 0, 480, 80, 10);
    ln_linear_kernel<<<64 * 480 / RPB, 128, 0, stream>>>(v, lnv_g, lnv_b, Wv, bv, vbp,
                                                         attn_scale, 0, 480, 80, 10);

    dim3 agrid(64, 4, 4);
    attn_kernel<<<agrid, 64, 0, stream>>>(qb, kbp, vbp, attn);

    proj_kernel<<<4096 / RPB, 128, 0, stream>>>(attn, Wp, bp, skip, out);
}

// Round 4
// 233.045 us; speedup vs baseline: 2.6623x; 1.2288x over previous
//
#include <hip/hip_runtime.h>

#define D 128
#define LN_EPS 1e-5f
#define RPB 16

#define VSTRD 244   // Vt row stride in dwords (976 B, 16B-aligned, even spread)
#define PSTRD 20    // P row stride in dwords (80 B, 16B-aligned)
#define XSTRS 136   // xn LDS row stride in shorts (272 B, 16B-aligned)

typedef __attribute__((ext_vector_type(8))) short short8;
typedef __attribute__((ext_vector_type(4))) float f32x4;

static __device__ __forceinline__ unsigned short f2bf(float f) {
    union { float f; unsigned u; } v; v.f = f;
    unsigned r = v.u + 0x7fffu + ((v.u >> 16) & 1u);   // RTNE
    return (unsigned short)(r >> 16);
}
static __device__ __forceinline__ unsigned pack2(float a, float b) {
    return (unsigned)f2bf(a) | ((unsigned)f2bf(b) << 16);
}

// ---------------------------------------------------------------------------
// W prep: fp32 [in=128][out=128] -> bf16 [out][in] for Wq,Wk,Wv.
// block = one out-column of one W; 64 threads pack 2 in-rows each.
// ---------------------------------------------------------------------------
__global__ __launch_bounds__(64)
void wprep_kernel(const float* __restrict__ Wq, const float* __restrict__ Wk,
                  const float* __restrict__ Wv, unsigned* __restrict__ Wt)
{
    const int w = blockIdx.x >> 7;        // 0..2
    const int o = blockIdx.x & 127;       // out col
    const float* W = (w == 0) ? Wq : (w == 1) ? Wk : Wv;
    const int t = threadIdx.x;            // 0..63
    const float a = W[(2 * t) * 128 + o];
    const float b = W[(2 * t + 1) * 128 + o];
    Wt[((size_t)w * 128 + o) * 64 + t] = pack2(a, b);
}

// ---------------------------------------------------------------------------
// LayerNorm + Linear (128 -> 128), 16 rows/block, 128 threads, bf16 I/O on
// the GEMM side. Phase A: LN (proven round-3 code). Phase B: MFMA —
// D = Wt·xn^T so out-cols land in reg index (packed ushort4 stores).
// Wave wv handles out-cols wv*64..wv*64+63 (4 otiles).
// ---------------------------------------------------------------------------
__global__ __launch_bounds__(128)
void ln_linear_kernel(const float* __restrict__ in,
                      const float* __restrict__ g,
                      const float* __restrict__ bvec,
                      const unsigned short* __restrict__ Wt,  // bf16 [out][in]
                      const float* __restrict__ bias,
                      unsigned short* __restrict__ out,       // bf16 [row][128]
                      const float* __restrict__ scale_p,
                      int use_scale,
                      int perL, int w1w2, int w2d)
{
    const int tid  = threadIdx.x;
    const int wave = tid >> 6;
    const int lane = tid & 63;
    const int base = blockIdx.x * RPB;

    __shared__ __align__(16) unsigned short xs[16 * XSTRS];
    __shared__ float red1[2][RPB];
    __shared__ float red2[2][RPB];

    // ---- Phase A: LN over 16 rows ----
    float xv[RPB];
    #pragma unroll
    for (int r = 0; r < RPB; ++r) {
        const int row = base + r;
        const int l   = row / perL;
        const int j   = row - l * perL;
        const int n   = j / w1w2;
        const int rem = j - n * w1w2;
        const int w1  = rem / w2d;
        const int w2  = rem - w1 * w2d;
        const int X   = l >> 3, Y = l & 7;
        const size_t inoff =
            ((size_t)(((n * 8 + X) * 8 + Y) * 8 + w1) * (size_t)w2d + (size_t)w2) * (size_t)D;
        xv[r] = in[inoff + tid];
    }

    #pragma unroll
    for (int r = 0; r < RPB; ++r) {
        float s1 = xv[r];
        float s2 = xv[r] * xv[r];
        #pragma unroll
        for (int o = 32; o > 0; o >>= 1) {
            s1 += __shfl_down(s1, o, 64);
            s2 += __shfl_down(s2, o, 64);
        }
        if (lane == 0) { red1[wave][r] = s1; red2[wave][r] = s2; }
    }
    __syncthreads();

    const float gt = g[tid], bt = bvec[tid];
    #pragma unroll
    for (int r = 0; r < RPB; ++r) {
        const float mu  = (red1[0][r] + red1[1][r]) * (1.0f / 128.0f);
        const float ms  = (red2[0][r] + red2[1][r]) * (1.0f / 128.0f);
        const float var = ms - mu * mu;
        const float rstd = rsqrtf(var + LN_EPS);
        xs[r * XSTRS + tid] = f2bf((xv[r] - mu) * rstd * gt + bt);
    }
    __syncthreads();

    // ---- Phase B: MFMA GEMM, D = Wt · xn^T ----
    const int m16 = tid & 15;
    const int gq  = (tid >> 4) & 3;
    const int wbase = wave * 64;          // out-col base for this wave

    short8 bx[4];
    #pragma unroll
    for (int kt = 0; kt < 4; ++kt)
        bx[kt] = *(const short8*)&xs[m16 * XSTRS + kt * 32 + gq * 8];

    f32x4 acc[4] = {{0,0,0,0},{0,0,0,0},{0,0,0,0},{0,0,0,0}};
    #pragma unroll
    for (int kt = 0; kt < 4; ++kt) {
        #pragma unroll
        for (int ot = 0; ot < 4; ++ot) {
            const short8 aw = *(const short8*)&Wt[
                (size_t)(wbase + ot * 16 + m16) * 128 + kt * 32 + gq * 8];
            acc[ot] = __builtin_amdgcn_mfma_f32_16x16x32_bf16(aw, bx[kt], acc[ot], 0, 0, 0);
        }
    }

    float s = 1.0f;
    if (use_scale) s = scale_p[0] * 0.17677669529663687f;  // * dh^-0.5

    #pragma unroll
    for (int ot = 0; ot < 4; ++ot) {
        const float4 bb = ((const float4*)bias)[(wbase + ot * 16) / 4 + gq];
        float v0 = acc[ot][0] + bb.x;
        float v1 = acc[ot][1] + bb.y;
        float v2 = acc[ot][2] + bb.z;
        float v3 = acc[ot][3] + bb.w;
        if (use_scale) { v0 *= s; v1 *= s; v2 *= s; v3 *= s; }
        ushort4 pk = make_ushort4(f2bf(v0), f2bf(v1), f2bf(v2), f2bf(v3));
        *(ushort4*)&out[(size_t)(base + m16) * 128 + wbase + ot * 16 + gq * 4] = pk;
    }
}

// ---------------------------------------------------------------------------
// Flash attention. Block = (l, h, qhalf), 384 threads (6 waves).
// Wave handles 2 q-tiles of 16 queries; K processed in 15 chunks of 32 keys.
//   S^T = K·Q^T   (query = C/D col = lane&15 — matches softmax lanes)
//   O^T = V^T·P^T (query = C/D col — alpha/linv lane-uniform, no shuffles)
// P^T B-frag built via per-wave LDS transpose (dword writes, b128 reads,
// wave-coherent: no barrier).
// ---------------------------------------------------------------------------
__global__ __launch_bounds__(384)
void attn_kernel(const unsigned short* __restrict__ qb,
                 const unsigned short* __restrict__ kb,
                 const unsigned short* __restrict__ vb,
                 float* __restrict__ out)
{
    __shared__ __align__(16) unsigned Vt[32 * VSTRD];        // 31232 B
    __shared__ __align__(16) unsigned Pall[6 * 16 * PSTRD];  // 7680 B

    const int l     = blockIdx.x;    // 0..63
    const int h     = blockIdx.y;    // 0..3
    const int qhalf = blockIdx.z;    // 0..1
    const int t     = threadIdx.x;
    const int wv    = t >> 6;
    const int lane  = t & 63;
    const int m16   = lane & 15;
    const int g     = lane >> 4;

    // ---- stage V^T, key-pair packed (2 keys per dword) ----
    {
        const int kpair = lane >> 3;           // 0..7
        const int c4    = (lane & 7) * 4;      // dcol group 0..28
        const unsigned short* vsrc = vb + ((size_t)l * 480) * 128 + h * 32 + c4;
        for (int p = wv * 5; p < wv * 5 + 5; ++p) {
            const int k0 = p * 16 + kpair * 2;
            const ushort4 va = *(const ushort4*)(vsrc + (size_t)k0 * 128);
            const ushort4 vc = *(const ushort4*)(vsrc + (size_t)(k0 + 1) * 128);
            const int dw = p * 8 + kpair;
            Vt[(c4 + 0) * VSTRD + dw] = (unsigned)va.x | ((unsigned)vc.x << 16);
            Vt[(c4 + 1) * VSTRD + dw] = (unsigned)va.y | ((unsigned)vc.y << 16);
            Vt[(c4 + 2) * VSTRD + dw] = (unsigned)va.z | ((unsigned)vc.z << 16);
            Vt[(c4 + 3) * VSTRD + dw] = (unsigned)va.w | ((unsigned)vc.w << 16);
        }
    }
    __syncthreads();

    const unsigned short* VtS = (const unsigned short*)Vt;   // row stride 488 shorts
    unsigned* P = &Pall[wv * 16 * PSTRD];
    const unsigned short* PS = (const unsigned short*)P;     // row stride 40 shorts

    const short* kq = (const short*)kb;
    const short* qs = (const short*)qb;
    const size_t lk = (size_t)l * 480;

    for (int qt = 0; qt < 2; ++qt) {
        const int qrow0 = qhalf * 192 + wv * 32 + qt * 16;
        const short8 bq = *(const short8*)(
            qs + ((size_t)(l * 384 + qrow0 + m16)) * 128 + h * 32 + g * 8);

        f32x4 o0 = {0.f, 0.f, 0.f, 0.f};
        f32x4 o1 = {0.f, 0.f, 0.f, 0.f};
        float mrun = -1e30f, lpart = 0.f;

        #pragma unroll 2
        for (int kc = 0; kc < 15; ++kc) {
            const short8 a0 = *(const short8*)(
                kq + (lk + kc * 32 + m16) * 128 + h * 32 + g * 8);
            const short8 a1 = *(const short8*)(
                kq + (lk + kc * 32 + 16 + m16) * 128 + h * 32 + g * 8);
            const f32x4 z = {0.f, 0.f, 0.f, 0.f};
            const f32x4 s0 = __builtin_amdgcn_mfma_f32_16x16x32_bf16(a0, bq, z, 0, 0, 0);
            const f32x4 s1 = __builtin_amdgcn_mfma_f32_16x16x32_bf16(a1, bq, z, 0, 0, 0);

            float cmax = fmaxf(fmaxf(fmaxf(s0[0], s0[1]), fmaxf(s0[2], s0[3])),
                               fmaxf(fmaxf(s1[0], s1[1]), fmaxf(s1[2], s1[3])));
            cmax = fmaxf(cmax, __shfl_xor(cmax, 16, 64));
            cmax = fmaxf(cmax, __shfl_xor(cmax, 32, 64));
            const float mnew  = fmaxf(mrun, cmax);
            const float alpha = __expf(mrun - mnew);   // 0 on first chunk
            mrun = mnew;

            float e0[4], e1[4], esum = 0.f;
            #pragma unroll
            for (int r = 0; r < 4; ++r) {
                e0[r] = __expf(s0[r] - mnew);
                e1[r] = __expf(s1[r] - mnew);
                esum += e0[r] + e1[r];
            }
            lpart = lpart * alpha + esum;

            // transpose P into per-wave LDS: row = query m16, keys packed 2/dword
            P[m16 * PSTRD + 2 * g + 0]     = pack2(e0[0], e0[1]);   // keys 4g,4g+1
            P[m16 * PSTRD + 2 * g + 1]     = pack2(e0[2], e0[3]);   // keys 4g+2,4g+3
            P[m16 * PSTRD + 8 + 2 * g + 0] = pack2(e1[0], e1[1]);   // keys 16+4g..
            P[m16 * PSTRD + 8 + 2 * g + 1] = pack2(e1[2], e1[3]);

            #pragma unroll
            for (int j = 0; j < 4; ++j) { o0[j] *= alpha; o1[j] *= alpha; }

            const short8 bp  = *(const short8*)&PS[m16 * 40 + g * 8];
            const short8 av0 = *(const short8*)&VtS[(size_t)m16 * 488 + kc * 32 + g * 8];
            const short8 av1 = *(const short8*)&VtS[(size_t)(16 + m16) * 488 + kc * 32 + g * 8];
            o0 = __builtin_amdgcn_mfma_f32_16x16x32_bf16(av0, bp, o0, 0, 0, 0);
            o1 = __builtin_amdgcn_mfma_f32_16x16x32_bf16(av1, bp, o1, 0, 0, 0);
        }

        float lsum = lpart;
        lsum += __shfl_xor(lsum, 16, 64);
        lsum += __shfl_xor(lsum, 32, 64);
        const float linv = 1.0f / lsum;

        f32x4 r0, r1;
        #pragma unroll
        for (int j = 0; j < 4; ++j) { r0[j] = o0[j] * linv; r1[j] = o1[j] * linv; }

        float* ob = out + ((size_t)(l * 384 + qrow0 + m16)) * 128 + h * 32;
        *(f32x4*)(ob + g * 4)      = r0;   // dcols g*4..+3
        *(f32x4*)(ob + 16 + g * 4) = r1;   // dcols 16+g*4..+3
    }
}

// ---------------------------------------------------------------------------
// mean over n (6 views) -> @ Wp + bp -> + skip (fp32, round-3 proven).
// ---------------------------------------------------------------------------
#define XSTR 20
__global__ __launch_bounds__(128)
void proj_kernel(const float* __restrict__ attn,
                 const float* __restrict__ Wp,
                 const float* __restrict__ bp,
                 const float* __restrict__ skip,
                 float* __restrict__ out)
{
    const int tid  = threadIdx.x;
    const int base = blockIdx.x * RPB;

    __shared__ float xs_t[128 * XSTR];

    float xn[RPB];
    #pragma unroll
    for (int r = 0; r < RPB; ++r) {
        const int row  = base + r;
        const int l    = row >> 6;
        const int qrem = row & 63;
        float acc = 0.f;
        #pragma unroll
        for (int n = 0; n < 6; ++n)
            acc += attn[((size_t)l * 384 + n * 64 + qrem) * D + tid];
        xn[r] = acc * (1.0f / 6.0f);
    }
    #pragma unroll
    for (int j = 0; j < 4; ++j) {
        *(float4*)(&xs_t[tid * XSTR + j * 4]) =
            make_float4(xn[j * 4 + 0], xn[j * 4 + 1], xn[j * 4 + 2], xn[j * 4 + 3]);
    }
    __syncthreads();

    const int cg = tid & 31;
    const int rg = tid >> 5;

    const float4 b4 = ((const float4*)bp)[cg];
    float4 a0 = b4, a1 = b4, a2 = b4, a3 = b4;

    const float4* Wv = (const float4*)Wp;
    #pragma unroll 4
    for (int i = 0; i < D; ++i) {
        const float4 w  = Wv[i * 32 + cg];
        const float4 xr = *(const float4*)(&xs_t[i * XSTR + rg * 4]);
        a0.x += w.x * xr.x; a0.y += w.y * xr.x; a0.z += w.z * xr.x; a0.w += w.w * xr.x;
        a1.x += w.x * xr.y; a1.y += w.y * xr.y; a1.z += w.z * xr.y; a1.w += w.w * xr.y;
        a2.x += w.x * xr.z; a2.y += w.y * xr.z; a2.z += w.z * xr.z; a2.w += w.w * xr.z;
        a3.x += w.x * xr.w; a3.y += w.y * xr.w; a3.z += w.z * xr.w; a3.w += w.w * xr.w;
    }

    const float4* skv = (const float4*)skip;
    float4* outv = (float4*)out;
    const int r0 = base + rg * 4;
    #pragma unroll
    for (int k = 0; k < 4; ++k) {
        float4 a = (k == 0) ? a0 : (k == 1) ? a1 : (k == 2) ? a2 : a3;
        const float4 sk = skv[(size_t)(r0 + k) * 32 + cg];
        outv[(size_t)(r0 + k) * 32 + cg] =
            make_float4(a.x + sk.x, a.y + sk.y, a.z + sk.z, a.w + sk.w);
    }
}

// ---------------------------------------------------------------------------
extern "C" void kernel_launch(void* const* d_in, const int* in_sizes, int n_in,
                              void* d_out, int out_size, void* d_ws, size_t ws_size,
                              hipStream_t stream)
{
    const float* q          = (const float*)d_in[0];
    const float* k          = (const float*)d_in[1];
    const float* v          = (const float*)d_in[2];
    const float* skip       = (const float*)d_in[3];
    const float* attn_scale = (const float*)d_in[4];
    const float* lnq_g      = (const float*)d_in[5];
    const float* lnq_b      = (const float*)d_in[6];
    const float* Wq         = (const float*)d_in[7];
    const float* bq         = (const float*)d_in[8];
    const float* lnk_g      = (const float*)d_in[9];
    const float* lnk_b      = (const float*)d_in[10];
    const float* Wk         = (const float*)d_in[11];
    const float* bk         = (const float*)d_in[12];
    const float* lnv_g      = (const float*)d_in[13];
    const float* lnv_b      = (const float*)d_in[14];
    const float* Wv         = (const float*)d_in[15];
    const float* bv         = (const float*)d_in[16];
    const float* Wp         = (const float*)d_in[17];
    const float* bp         = (const float*)d_in[18];

    float* out = (float*)d_out;
    char*  wsb = (char*)d_ws;

    // ws layout (bytes)
    unsigned short* qbuf = (unsigned short*)(wsb);              //  6,291,456
    unsigned short* kbuf = (unsigned short*)(wsb + 6291456);    //  7,864,320
    unsigned short* vbuf = (unsigned short*)(wsb + 14155776);   //  7,864,320
    unsigned short* Wt   = (unsigned short*)(wsb + 22020096);   //     98,304
    float*          attn = (float*)        (wsb + 22118400);    // 12,582,912

    unsigned short* Wtq = Wt;
    unsigned short* Wtk = Wt + 16384;
    unsigned short* Wtv = Wt + 32768;

    wprep_kernel<<<384, 64, 0, stream>>>(Wq, Wk, Wv, (unsigned*)Wt);

    ln_linear_kernel<<<24576 / RPB, 128, 0, stream>>>(q, lnq_g, lnq_b, Wtq, bq, qbuf,
                                                      attn_scale, 1, 384, 64, 8);
    ln_linear_kernel<<<30720 / RPB, 128, 0, stream>>>(k, lnk_g, lnk_b, Wtk, bk, kbuf,
                                                      attn_scale, 0, 480, 80, 10);
    ln_linear_kernel<<<30720 / RPB, 128, 0, stream>>>(v, lnv_g, lnv_b, Wtv, bv, vbuf,
                                                      attn_scale, 0, 480, 80, 10);

    dim3 agrid(64, 4, 2);
    attn_kernel<<<agrid, 384, 0, stream>>>(qbuf, kbuf, vbuf, attn);

    proj_kernel<<<4096 / RPB, 128, 0, stream>>>(attn, Wp, bp, skip, out);
}

// Round 5
// 193.506 us; speedup vs baseline: 3.2063x; 1.2043x over previous
//
#include <hip/hip_runtime.h>

#define D 128
#define LN_EPS 1e-5f

#define VSTRD 244   // Vt row stride in dwords (16B-aligned, even superbank spread)
#define PSTRD 20    // P row stride in dwords (16B-aligned)

typedef __attribute__((ext_vector_type(8))) short short8;
typedef __attribute__((ext_vector_type(4))) float f32x4;

static __device__ __forceinline__ unsigned short f2bf(float f) {
    union { float f; unsigned u; } v; v.f = f;
    unsigned r = v.u + 0x7fffu + ((v.u >> 16) & 1u);   // RTNE
    return (unsigned short)(r >> 16);
}
static __device__ __forceinline__ unsigned pack2(float a, float b) {
    return (unsigned)f2bf(a) | ((unsigned)f2bf(b) << 16);
}
static __device__ __forceinline__ float bf2f(unsigned short u) {
    union { unsigned u; float f; } v; v.u = ((unsigned)u) << 16; return v.f;
}

// ---------------------------------------------------------------------------
// W prep. For q/k/v: Wt = diag(g)·W as bf16 [out][in]; c1 = g^T W; c2 = beta^T W
// + bias (LN folded into GEMM epilogue: y = rstd*(x·Wt) - rstd*mu*c1 + c2).
// For Wp: plain bf16 transpose [out][in].
// Grid: 512 blocks of 64 (w = block>>7: 0=q,1=k,2=v,3=Wp; o = block&127).
// ---------------------------------------------------------------------------
__global__ __launch_bounds__(64)
void wprep_kernel(const float* __restrict__ Wq, const float* __restrict__ Wk,
                  const float* __restrict__ Wv, const float* __restrict__ Wp,
                  const float* __restrict__ gq, const float* __restrict__ betaq,
                  const float* __restrict__ biasq,
                  const float* __restrict__ gk, const float* __restrict__ betak,
                  const float* __restrict__ biask,
                  const float* __restrict__ gv, const float* __restrict__ betav,
                  const float* __restrict__ biasv,
                  unsigned* __restrict__ Wt, unsigned* __restrict__ Wpt,
                  float* __restrict__ c1, float* __restrict__ c2)
{
    const int id = blockIdx.x;
    const int w  = id >> 7;
    const int o  = id & 127;
    const int t  = threadIdx.x;
    if (w < 3) {
        const float* W  = (w == 0) ? Wq : (w == 1) ? Wk : Wv;
        const float* gg = (w == 0) ? gq : (w == 1) ? gk : gv;
        const float* bb = (w == 0) ? betaq : (w == 1) ? betak : betav;
        const float* bi = (w == 0) ? biasq : (w == 1) ? biask : biasv;
        const float w0 = W[(2 * t) * 128 + o];
        const float w1 = W[(2 * t + 1) * 128 + o];
        const float g0 = gg[2 * t], g1 = gg[2 * t + 1];
        const float b0 = bb[2 * t], b1 = bb[2 * t + 1];
        Wt[((size_t)w * 128 + o) * 64 + t] = pack2(g0 * w0, g1 * w1);
        float s1 = g0 * w0 + g1 * w1;
        float s2 = b0 * w0 + b1 * w1;
        #pragma unroll
        for (int off = 32; off > 0; off >>= 1) {
            s1 += __shfl_down(s1, off, 64);
            s2 += __shfl_down(s2, off, 64);
        }
        if (t == 0) { c1[w * 128 + o] = s1; c2[w * 128 + o] = s2 + bi[o]; }
    } else {
        Wpt[(size_t)o * 64 + t] = pack2(Wp[(2 * t) * 128 + o], Wp[(2 * t + 1) * 128 + o]);
    }
}

// ---------------------------------------------------------------------------
// Fused LN+Linear, all-MFMA. Block = 256 thr (4 waves), wave = 16 rows.
// x fragments read straight from global (no LDS staging): the same frag is
//   A of X·1 (row sums), A and B of X·X^T (diag = row sumsq), B of Wt·x^T.
// LN folded into epilogue: y = rstd*acc - (rstd*mu)*c1[out] + c2[out].
// Divisors are template constants -> magic multiplies, no v_div sequences.
// ---------------------------------------------------------------------------
template<int PERL, int W1W2, int W2D>
__global__ __launch_bounds__(256)
void ln_linear_kernel(const float* __restrict__ in,
                      const unsigned short* __restrict__ Wt,  // diag(g)W bf16 [out][128]
                      const float* __restrict__ c1,
                      const float* __restrict__ c2,
                      unsigned short* __restrict__ out,       // bf16 [row][128]
                      const float* __restrict__ scale_p, int use_scale)
{
    const int t    = threadIdx.x;
    const int wv   = t >> 6;
    const int lane = t & 63;
    const int m16  = lane & 15;
    const int g    = lane >> 4;
    const int row  = blockIdx.x * 64 + wv * 16 + m16;

    // output-row -> input-offset (compile-time divisors)
    const int l   = row / PERL, j = row - l * PERL;
    const int n   = j / W1W2, rem = j - n * W1W2;
    const int w1  = rem / W2D, w2 = rem - w1 * W2D;
    const int X   = l >> 3, Y = l & 7;
    const float* xrow = in + ((size_t)(((n * 8 + X) * 8 + Y) * 8 + w1) * W2D + w2) * D;

    short8 xf[4];
    #pragma unroll
    for (int kt = 0; kt < 4; ++kt) {
        const float4 a = *(const float4*)(xrow + kt * 32 + g * 8);
        const float4 b = *(const float4*)(xrow + kt * 32 + g * 8 + 4);
        short8 vv;
        vv[0] = (short)f2bf(a.x); vv[1] = (short)f2bf(a.y);
        vv[2] = (short)f2bf(a.z); vv[3] = (short)f2bf(a.w);
        vv[4] = (short)f2bf(b.x); vv[5] = (short)f2bf(b.y);
        vv[6] = (short)f2bf(b.z); vv[7] = (short)f2bf(b.w);
        xf[kt] = vv;
    }

    // ---- stats via MFMA: rowsum = X·1, sumsq = diag(X·X^T) ----
    short8 ones;
    #pragma unroll
    for (int jj = 0; jj < 8; ++jj) ones[jj] = (short)0x3F80;  // bf16 1.0
    f32x4 sums = {0.f, 0.f, 0.f, 0.f}, gram = {0.f, 0.f, 0.f, 0.f};
    #pragma unroll
    for (int kt = 0; kt < 4; ++kt) {
        sums = __builtin_amdgcn_mfma_f32_16x16x32_bf16(xf[kt], ones, sums, 0, 0, 0);
        gram = __builtin_amdgcn_mfma_f32_16x16x32_bf16(xf[kt], xf[kt], gram, 0, 0, 0);
    }
    __shared__ float smu[4][16], ssq[4][16];
    // lane holds D rows 4g..4g+3 at col m16; diag needs row==col==m16 -> g==m16>>2
    if (g == (m16 >> 2)) {
        smu[wv][m16] = sums[m16 & 3];
        ssq[wv][m16] = gram[m16 & 3];
    }
    __syncthreads();
    const float mu   = smu[wv][m16] * (1.0f / 128.0f);
    const float msq  = ssq[wv][m16] * (1.0f / 128.0f);
    const float rstd = rsqrtf(msq - mu * mu + LN_EPS);
    const float rmu  = rstd * mu;

    // ---- GEMM: D[out][row] = Wt · x^T ----
    f32x4 acc[8] = {{0,0,0,0},{0,0,0,0},{0,0,0,0},{0,0,0,0},
                    {0,0,0,0},{0,0,0,0},{0,0,0,0},{0,0,0,0}};
    #pragma unroll
    for (int kt = 0; kt < 4; ++kt) {
        #pragma unroll
        for (int ot = 0; ot < 8; ++ot) {
            const short8 aw = *(const short8*)&Wt[
                (size_t)(ot * 16 + m16) * 128 + kt * 32 + g * 8];
            acc[ot] = __builtin_amdgcn_mfma_f32_16x16x32_bf16(aw, xf[kt], acc[ot], 0, 0, 0);
        }
    }

    const float s = use_scale ? scale_p[0] * 0.17677669529663687f : 1.0f;

    #pragma unroll
    for (int ot = 0; ot < 8; ++ot) {
        const int ob = ot * 16 + g * 4;   // lane's 4 consecutive out cols
        const float4 cc1 = *(const float4*)&c1[ob];
        const float4 cc2 = *(const float4*)&c2[ob];
        float v0 = rstd * acc[ot][0] - rmu * cc1.x + cc2.x;
        float v1 = rstd * acc[ot][1] - rmu * cc1.y + cc2.y;
        float v2 = rstd * acc[ot][2] - rmu * cc1.z + cc2.z;
        float v3 = rstd * acc[ot][3] - rmu * cc1.w + cc2.w;
        if (use_scale) { v0 *= s; v1 *= s; v2 *= s; v3 *= s; }
        *(ushort4*)&out[(size_t)row * D + ob] =
            make_ushort4(f2bf(v0), f2bf(v1), f2bf(v2), f2bf(v3));
    }
}

// ---------------------------------------------------------------------------
// Flash attention, no-max softmax. Scores are bounded (LN'd q,k; 32-dim dot *
// 0.21 -> |s| <~ 8, exp safe in fp32; softmax is shift-invariant so skipping
// the max subtraction is mathematically exact within fp32 range).
// Grid (64 l, 4 h, 4 qz) x 384 thr (6 waves, 16 queries each).
//   S^T = K·Q^T  (query = C/D col -> softmax stats lane-uniform)
//   O^T = V^T·P^T (P^T built via per-wave LDS transpose, b64 writes)
// Output bf16.
// ---------------------------------------------------------------------------
__global__ __launch_bounds__(384, 6)
void attn_kernel(const unsigned short* __restrict__ qb,
                 const unsigned short* __restrict__ kb,
                 const unsigned short* __restrict__ vb,
                 unsigned short* __restrict__ out)
{
    __shared__ __align__(16) unsigned Vt[32 * VSTRD];        // 31232 B
    __shared__ __align__(16) unsigned Pall[6 * 16 * PSTRD];  // 7680 B

    const int l    = blockIdx.x;    // 0..63
    const int h    = blockIdx.y;    // 0..3
    const int qz   = blockIdx.z;    // 0..3
    const int t    = threadIdx.x;
    const int wv   = t >> 6;
    const int lane = t & 63;
    const int m16  = lane & 15;
    const int g    = lane >> 4;

    // ---- stage V^T, key-pair packed ----
    {
        const int kpair = lane >> 3;
        const int c4    = (lane & 7) * 4;
        const unsigned short* vsrc = vb + ((size_t)l * 480) * 128 + h * 32 + c4;
        for (int p = wv * 5; p < wv * 5 + 5; ++p) {
            const int k0 = p * 16 + kpair * 2;
            const ushort4 va = *(const ushort4*)(vsrc + (size_t)k0 * 128);
            const ushort4 vc = *(const ushort4*)(vsrc + (size_t)(k0 + 1) * 128);
            const int dw = p * 8 + kpair;
            Vt[(c4 + 0) * VSTRD + dw] = (unsigned)va.x | ((unsigned)vc.x << 16);
            Vt[(c4 + 1) * VSTRD + dw] = (unsigned)va.y | ((unsigned)vc.y << 16);
            Vt[(c4 + 2) * VSTRD + dw] = (unsigned)va.z | ((unsigned)vc.z << 16);
            Vt[(c4 + 3) * VSTRD + dw] = (unsigned)va.w | ((unsigned)vc.w << 16);
        }
    }
    __syncthreads();

    const unsigned short* VtS = (const unsigned short*)Vt;   // stride 488 shorts
    unsigned* P = &Pall[wv * 16 * PSTRD];
    const unsigned short* PS = (const unsigned short*)P;     // stride 40 shorts

    const short* kq = (const short*)kb;
    const short* qs = (const short*)qb;
    const size_t lk = (size_t)l * 480;

    const int qrow0 = qz * 96 + wv * 16;
    const short8 bq = *(const short8*)(
        qs + ((size_t)(l * 384 + qrow0 + m16)) * 128 + h * 32 + g * 8);

    f32x4 o0 = {0.f, 0.f, 0.f, 0.f};
    f32x4 o1 = {0.f, 0.f, 0.f, 0.f};
    float esum = 0.f;

    #pragma unroll 3
    for (int kc = 0; kc < 15; ++kc) {
        const short8 a0 = *(const short8*)(
            kq + (lk + kc * 32 + m16) * 128 + h * 32 + g * 8);
        const short8 a1 = *(const short8*)(
            kq + (lk + kc * 32 + 16 + m16) * 128 + h * 32 + g * 8);
        const f32x4 z = {0.f, 0.f, 0.f, 0.f};
        const f32x4 s0 = __builtin_amdgcn_mfma_f32_16x16x32_bf16(a0, bq, z, 0, 0, 0);
        const f32x4 s1 = __builtin_amdgcn_mfma_f32_16x16x32_bf16(a1, bq, z, 0, 0, 0);

        float e0[4], e1[4];
        #pragma unroll
        for (int r = 0; r < 4; ++r) {
            e0[r] = __expf(s0[r]);
            e1[r] = __expf(s1[r]);
            esum += e0[r] + e1[r];
        }

        // transpose P (query-major) via per-wave LDS, b64 writes (conflict-free)
        uint2 pk0, pk1;
        pk0.x = pack2(e0[0], e0[1]); pk0.y = pack2(e0[2], e0[3]);
        pk1.x = pack2(e1[0], e1[1]); pk1.y = pack2(e1[2], e1[3]);
        *(uint2*)&P[m16 * PSTRD + 2 * g]     = pk0;   // keys 4g..4g+3
        *(uint2*)&P[m16 * PSTRD + 8 + 2 * g] = pk1;   // keys 16+4g..19+4g

        const short8 bp  = *(const short8*)&PS[m16 * 40 + g * 8];
        const short8 av0 = *(const short8*)&VtS[(size_t)m16 * 488 + kc * 32 + g * 8];
        const short8 av1 = *(const short8*)&VtS[(size_t)(16 + m16) * 488 + kc * 32 + g * 8];
        o0 = __builtin_amdgcn_mfma_f32_16x16x32_bf16(av0, bp, o0, 0, 0, 0);
        o1 = __builtin_amdgcn_mfma_f32_16x16x32_bf16(av1, bp, o1, 0, 0, 0);
    }

    float lsum = esum;
    lsum += __shfl_xor(lsum, 16, 64);
    lsum += __shfl_xor(lsum, 32, 64);
    const float linv = 1.0f / lsum;

    unsigned short* ob = out + ((size_t)(l * 384 + qrow0 + m16)) * 128 + h * 32;
    *(ushort4*)(ob + g * 4) = make_ushort4(
        f2bf(o0[0] * linv), f2bf(o0[1] * linv), f2bf(o0[2] * linv), f2bf(o0[3] * linv));
    *(ushort4*)(ob + 16 + g * 4) = make_ushort4(
        f2bf(o1[0] * linv), f2bf(o1[1] * linv), f2bf(o1[2] * linv), f2bf(o1[3] * linv));
}

// ---------------------------------------------------------------------------
// proj: mean over 6 views (bf16 in) -> @ Wp (MFMA, bf16) -> + bp + skip (fp32).
// Block 256 thr = 4 waves: 2 row-groups x 2 out-halves; 32 out-rows/block.
// ---------------------------------------------------------------------------
__global__ __launch_bounds__(256)
void proj_kernel(const unsigned short* __restrict__ attnb,
                 const unsigned short* __restrict__ Wpt,   // bf16 [out][in]
                 const float* __restrict__ bp,
                 const float* __restrict__ skip,
                 float* __restrict__ out)
{
    const int t     = threadIdx.x;
    const int wv    = t >> 6;
    const int lane  = t & 63;
    const int m16   = lane & 15;
    const int g     = lane >> 4;
    const int rgrp  = wv >> 1;
    const int ohalf = wv & 1;

    const int row  = blockIdx.x * 32 + rgrp * 16 + m16;  // out row 0..4095
    const int l    = row >> 6;
    const int qrem = row & 63;

    // B-frags: mean over 6 views of the row's d-slice, packed bf16
    short8 xf[4];
    #pragma unroll
    for (int kt = 0; kt < 4; ++kt) {
        float m[8] = {0,0,0,0,0,0,0,0};
        #pragma unroll
        for (int n = 0; n < 6; ++n) {
            const short8 vv = *(const short8*)(
                attnb + ((size_t)(l * 384 + n * 64 + qrem)) * 128 + kt * 32 + g * 8);
            #pragma unroll
            for (int jj = 0; jj < 8; ++jj)
                m[jj] += bf2f((unsigned short)vv[jj]);
        }
        short8 pk;
        #pragma unroll
        for (int jj = 0; jj < 8; ++jj) pk[jj] = (short)f2bf(m[jj] * (1.0f / 6.0f));
        xf[kt] = pk;
    }

    f32x4 acc[4] = {{0,0,0,0},{0,0,0,0},{0,0,0,0},{0,0,0,0}};
    #pragma unroll
    for (int kt = 0; kt < 4; ++kt) {
        #pragma unroll
        for (int ot = 0; ot < 4; ++ot) {
            const short8 aw = *(const short8*)&Wpt[
                (size_t)(ohalf * 64 + ot * 16 + m16) * 128 + kt * 32 + g * 8];
            acc[ot] = __builtin_amdgcn_mfma_f32_16x16x32_bf16(aw, xf[kt], acc[ot], 0, 0, 0);
        }
    }

    #pragma unroll
    for (int ot = 0; ot < 4; ++ot) {
        const int ob = ohalf * 64 + ot * 16 + g * 4;
        const float4 bb = *(const float4*)&bp[ob];
        const float4 sk = *(const float4*)&skip[(size_t)row * D + ob];
        float4 r;
        r.x = acc[ot][0] + bb.x + sk.x;
        r.y = acc[ot][1] + bb.y + sk.y;
        r.z = acc[ot][2] + bb.z + sk.z;
        r.w = acc[ot][3] + bb.w + sk.w;
        *(float4*)&out[(size_t)row * D + ob] = r;
    }
}

// ---------------------------------------------------------------------------
extern "C" void kernel_launch(void* const* d_in, const int* in_sizes, int n_in,
                              void* d_out, int out_size, void* d_ws, size_t ws_size,
                              hipStream_t stream)
{
    const float* q          = (const float*)d_in[0];
    const float* k          = (const float*)d_in[1];
    const float* v          = (const float*)d_in[2];
    const float* skip       = (const float*)d_in[3];
    const float* attn_scale = (const float*)d_in[4];
    const float* lnq_g      = (const float*)d_in[5];
    const float* lnq_b      = (const float*)d_in[6];
    const float* Wq         = (const float*)d_in[7];
    const float* bq         = (const float*)d_in[8];
    const float* lnk_g      = (const float*)d_in[9];
    const float* lnk_b      = (const float*)d_in[10];
    const float* Wk         = (const float*)d_in[11];
    const float* bk         = (const float*)d_in[12];
    const float* lnv_g      = (const float*)d_in[13];
    const float* lnv_b      = (const float*)d_in[14];
    const float* Wv         = (const float*)d_in[15];
    const float* bv         = (const float*)d_in[16];
    const float* Wp         = (const float*)d_in[17];
    const float* bp         = (const float*)d_in[18];

    float* out = (float*)d_out;
    char*  wsb = (char*)d_ws;

    // ws layout (bytes)
    unsigned short* qbuf = (unsigned short*)(wsb);              //  6,291,456
    unsigned short* kbuf = (unsigned short*)(wsb + 6291456);    //  7,864,320
    unsigned short* vbuf = (unsigned short*)(wsb + 14155776);   //  7,864,320
    unsigned short* Wt   = (unsigned short*)(wsb + 22020096);   //     98,304
    unsigned short* Wpt  = (unsigned short*)(wsb + 22118400);   //     32,768
    float*          c1   = (float*)        (wsb + 22151168);    //      1,536
    float*          c2   = (float*)        (wsb + 22152704);    //      1,536
    unsigned short* attnb= (unsigned short*)(wsb + 22154240);   //  6,291,456

    wprep_kernel<<<512, 64, 0, stream>>>(Wq, Wk, Wv, Wp,
                                         lnq_g, lnq_b, bq,
                                         lnk_g, lnk_b, bk,
                                         lnv_g, lnv_b, bv,
                                         (unsigned*)Wt, (unsigned*)Wpt, c1, c2);

    ln_linear_kernel<384, 64, 8><<<384, 256, 0, stream>>>(
        q, Wt, c1, c2, qbuf, attn_scale, 1);
    ln_linear_kernel<480, 80, 10><<<480, 256, 0, stream>>>(
        k, Wt + 16384, c1 + 128, c2 + 128, kbuf, attn_scale, 0);
    ln_linear_kernel<480, 80, 10><<<480, 256, 0, stream>>>(
        v, Wt + 32768, c1 + 256, c2 + 256, vbuf, attn_scale, 0);

    dim3 agrid(64, 4, 4);
    attn_kernel<<<agrid, 384, 0, stream>>>(qbuf, kbuf, vbuf, attnb);

    proj_kernel<<<128, 256, 0, stream>>>(attnb, Wpt, bp, skip, out);
}

// Round 6
// 188.823 us; speedup vs baseline: 3.2858x; 1.0248x over previous
//
#include <hip/hip_runtime.h>

#define D 128
#define LN_EPS 1e-5f
#define PSTRD 20    // P row stride in dwords (16B-aligned)

typedef __attribute__((ext_vector_type(8))) short short8;
typedef __attribute__((ext_vector_type(4))) float f32x4;

static __device__ __forceinline__ unsigned short f2bf(float f) {
    union { float f; unsigned u; } v; v.f = f;
    unsigned r = v.u + 0x7fffu + ((v.u >> 16) & 1u);   // RTNE
    return (unsigned short)(r >> 16);
}
static __device__ __forceinline__ unsigned pack2(float a, float b) {
    return (unsigned)f2bf(a) | ((unsigned)f2bf(b) << 16);
}
static __device__ __forceinline__ float bf2f(unsigned short u) {
    union { unsigned u; float f; } v; v.u = ((unsigned)u) << 16; return v.f;
}

// ---------------------------------------------------------------------------
// W prep (unchanged from R5): Wt = diag(g)W bf16 [out][in], c1 = g^T W,
// c2 = beta^T W + bias; Wpt = bf16 Wp^T.
// ---------------------------------------------------------------------------
__global__ __launch_bounds__(64)
void wprep_kernel(const float* __restrict__ Wq, const float* __restrict__ Wk,
                  const float* __restrict__ Wv, const float* __restrict__ Wp,
                  const float* __restrict__ gq, const float* __restrict__ betaq,
                  const float* __restrict__ biasq,
                  const float* __restrict__ gk, const float* __restrict__ betak,
                  const float* __restrict__ biask,
                  const float* __restrict__ gv, const float* __restrict__ betav,
                  const float* __restrict__ biasv,
                  unsigned* __restrict__ Wt, unsigned* __restrict__ Wpt,
                  float* __restrict__ c1, float* __restrict__ c2)
{
    const int id = blockIdx.x;
    const int w  = id >> 7;
    const int o  = id & 127;
    const int t  = threadIdx.x;
    if (w < 3) {
        const float* W  = (w == 0) ? Wq : (w == 1) ? Wk : Wv;
        const float* gg = (w == 0) ? gq : (w == 1) ? gk : gv;
        const float* bb = (w == 0) ? betaq : (w == 1) ? betak : betav;
        const float* bi = (w == 0) ? biasq : (w == 1) ? biask : biasv;
        const float w0 = W[(2 * t) * 128 + o];
        const float w1 = W[(2 * t + 1) * 128 + o];
        const float g0 = gg[2 * t], g1 = gg[2 * t + 1];
        const float b0 = bb[2 * t], b1 = bb[2 * t + 1];
        Wt[((size_t)w * 128 + o) * 64 + t] = pack2(g0 * w0, g1 * w1);
        float s1 = g0 * w0 + g1 * w1;
        float s2 = b0 * w0 + b1 * w1;
        #pragma unroll
        for (int off = 32; off > 0; off >>= 1) {
            s1 += __shfl_down(s1, off, 64);
            s2 += __shfl_down(s2, off, 64);
        }
        if (t == 0) { c1[w * 128 + o] = s1; c2[w * 128 + o] = s2 + bi[o]; }
    } else {
        Wpt[(size_t)o * 64 + t] = pack2(Wp[(2 * t) * 128 + o], Wp[(2 * t + 1) * 128 + o]);
    }
}

// ---------------------------------------------------------------------------
// LN+Linear body (all-MFMA, stats via X·1 and diag(X·X^T) — proven in R5).
// MODE 0: bf16 row-major out. MODE 1: + scale (q). MODE 2: transposed
// scatter to vtb[l][h][d][key] (v) so attention reads V^T straight from
// global with no LDS staging.
// ---------------------------------------------------------------------------
template<int PERL, int W1W2, int W2D, int MODE>
static __device__ __forceinline__
void ln_body(const float* __restrict__ in,
             const unsigned short* __restrict__ Wt,
             const float* __restrict__ c1, const float* __restrict__ c2,
             unsigned short* __restrict__ out,
             float scale, int rowbase, int t,
             float (*smu)[16], float (*ssq)[16])
{
    const int wv   = t >> 6;
    const int lane = t & 63;
    const int m16  = lane & 15;
    const int g    = lane >> 4;
    const int row  = rowbase + wv * 16 + m16;

    const int l   = row / PERL, j = row - l * PERL;
    const int n   = j / W1W2, rem = j - n * W1W2;
    const int w1  = rem / W2D, w2 = rem - w1 * W2D;
    const int X   = l >> 3, Y = l & 7;
    const float* xrow = in + ((size_t)(((n * 8 + X) * 8 + Y) * 8 + w1) * W2D + w2) * D;

    short8 xf[4];
    #pragma unroll
    for (int kt = 0; kt < 4; ++kt) {
        const float4 a = *(const float4*)(xrow + kt * 32 + g * 8);
        const float4 b = *(const float4*)(xrow + kt * 32 + g * 8 + 4);
        short8 vv;
        vv[0] = (short)f2bf(a.x); vv[1] = (short)f2bf(a.y);
        vv[2] = (short)f2bf(a.z); vv[3] = (short)f2bf(a.w);
        vv[4] = (short)f2bf(b.x); vv[5] = (short)f2bf(b.y);
        vv[6] = (short)f2bf(b.z); vv[7] = (short)f2bf(b.w);
        xf[kt] = vv;
    }

    short8 ones;
    #pragma unroll
    for (int jj = 0; jj < 8; ++jj) ones[jj] = (short)0x3F80;
    f32x4 sums = {0.f, 0.f, 0.f, 0.f}, gram = {0.f, 0.f, 0.f, 0.f};
    #pragma unroll
    for (int kt = 0; kt < 4; ++kt) {
        sums = __builtin_amdgcn_mfma_f32_16x16x32_bf16(xf[kt], ones, sums, 0, 0, 0);
        gram = __builtin_amdgcn_mfma_f32_16x16x32_bf16(xf[kt], xf[kt], gram, 0, 0, 0);
    }
    if (g == (m16 >> 2)) {
        smu[wv][m16] = sums[m16 & 3];
        ssq[wv][m16] = gram[m16 & 3];
    }
    __syncthreads();
    const float mu   = smu[wv][m16] * (1.0f / 128.0f);
    const float msq  = ssq[wv][m16] * (1.0f / 128.0f);
    const float rstd = rsqrtf(msq - mu * mu + LN_EPS);
    const float rmu  = rstd * mu;

    f32x4 acc[8] = {{0,0,0,0},{0,0,0,0},{0,0,0,0},{0,0,0,0},
                    {0,0,0,0},{0,0,0,0},{0,0,0,0},{0,0,0,0}};
    #pragma unroll
    for (int kt = 0; kt < 4; ++kt) {
        #pragma unroll
        for (int ot = 0; ot < 8; ++ot) {
            const short8 aw = *(const short8*)&Wt[
                (size_t)(ot * 16 + m16) * 128 + kt * 32 + g * 8];
            acc[ot] = __builtin_amdgcn_mfma_f32_16x16x32_bf16(aw, xf[kt], acc[ot], 0, 0, 0);
        }
    }

    #pragma unroll
    for (int ot = 0; ot < 8; ++ot) {
        const int ob = ot * 16 + g * 4;
        const float4 cc1 = *(const float4*)&c1[ob];
        const float4 cc2 = *(const float4*)&c2[ob];
        float v0 = rstd * acc[ot][0] - rmu * cc1.x + cc2.x;
        float v1 = rstd * acc[ot][1] - rmu * cc1.y + cc2.y;
        float v2 = rstd * acc[ot][2] - rmu * cc1.z + cc2.z;
        float v3 = rstd * acc[ot][3] - rmu * cc1.w + cc2.w;
        if (MODE == 1) { v0 *= scale; v1 *= scale; v2 *= scale; v3 *= scale; }
        if (MODE == 2) {
            // transposed scatter: vtb[((l*4 + d>>5)*32 + (d&31))*480 + key]
            const float vals[4] = {v0, v1, v2, v3};
            #pragma unroll
            for (int c = 0; c < 4; ++c) {
                const int d = ob + c;
                out[((size_t)((l * 4 + (d >> 5)) * 32 + (d & 31))) * 480 + j] = f2bf(vals[c]);
            }
        } else {
            *(ushort4*)&out[(size_t)row * D + ob] =
                make_ushort4(f2bf(v0), f2bf(v1), f2bf(v2), f2bf(v3));
        }
    }
}

// Fused q/k/v LN+Linear: one launch, block-uniform branch.
// blocks [0,384): q  [384,864): k  [864,1344): v
__global__ __launch_bounds__(256)
void ln_fused_kernel(const float* __restrict__ q, const float* __restrict__ k,
                     const float* __restrict__ v,
                     const unsigned short* __restrict__ Wt,
                     const float* __restrict__ c1, const float* __restrict__ c2,
                     unsigned short* __restrict__ qbuf,
                     unsigned short* __restrict__ kbuf,
                     unsigned short* __restrict__ vtb,
                     const float* __restrict__ scale_p)
{
    __shared__ float smu[4][16];
    __shared__ float ssq[4][16];
    const int bid = blockIdx.x;
    const int t   = threadIdx.x;
    if (bid < 384) {
        // fold attn_scale * dh^-0.5 * log2(e) into q (softmax via exp2)
        const float s = scale_p[0] * 0.17677669529663687f * 1.4426950408889634f;
        ln_body<384, 64, 8, 1>(q, Wt, c1, c2, qbuf, s, bid * 64, t, smu, ssq);
    } else if (bid < 864) {
        ln_body<480, 80, 10, 0>(k, Wt + 16384, c1 + 128, c2 + 128, kbuf,
                                1.0f, (bid - 384) * 64, t, smu, ssq);
    } else {
        ln_body<480, 80, 10, 2>(v, Wt + 32768, c1 + 256, c2 + 256, vtb,
                                1.0f, (bid - 864) * 64, t, smu, ssq);
    }
}

// ---------------------------------------------------------------------------
// Flash attention, zero staging, barrier-free. Grid (64 l, 4 h, 4 qz) x 384.
// K and V^T A-fragments read directly from global (kbuf row-major = A layout
// for K; vtb = A layout for V^T). Only LDS use: 1.25 KB/wave P-transpose.
// Softmax: no-max (scores bounded, LN'd inputs), exp2 with log2e pre-folded
// into q.  qz-siblings share an XCD (grid-linear %8 == l%8) for L2 reuse.
// ---------------------------------------------------------------------------
__global__ __launch_bounds__(384)
void attn_kernel(const unsigned short* __restrict__ qb,
                 const unsigned short* __restrict__ kb,
                 const unsigned short* __restrict__ vtb,
                 unsigned short* __restrict__ out)
{
    __shared__ __align__(16) unsigned Pall[6 * 16 * PSTRD];  // 7680 B

    const int l    = blockIdx.x;
    const int h    = blockIdx.y;
    const int qz   = blockIdx.z;
    const int t    = threadIdx.x;
    const int wv   = t >> 6;
    const int lane = t & 63;
    const int m16  = lane & 15;
    const int g    = lane >> 4;

    unsigned* P = &Pall[wv * 16 * PSTRD];
    const unsigned short* PS = (const unsigned short*)P;     // stride 40 shorts

    const int qrow0 = qz * 96 + wv * 16;
    const short8 bq = *(const short8*)(
        qb + ((size_t)(l * 384 + qrow0 + m16)) * 128 + h * 32 + g * 8);

    const unsigned short* kbase = kb + ((size_t)l * 480) * 128 + h * 32;
    const unsigned short* vbase = vtb + ((size_t)(l * 4 + h) * 32) * 480;

    f32x4 o0 = {0.f, 0.f, 0.f, 0.f};
    f32x4 o1 = {0.f, 0.f, 0.f, 0.f};
    float esum = 0.f;

    #pragma unroll 3
    for (int kc = 0; kc < 15; ++kc) {
        const short8 a0 = *(const short8*)(kbase + (size_t)(kc * 32 + m16) * 128 + g * 8);
        const short8 a1 = *(const short8*)(kbase + (size_t)(kc * 32 + 16 + m16) * 128 + g * 8);
        const f32x4 z = {0.f, 0.f, 0.f, 0.f};
        const f32x4 s0 = __builtin_amdgcn_mfma_f32_16x16x32_bf16(a0, bq, z, 0, 0, 0);
        const f32x4 s1 = __builtin_amdgcn_mfma_f32_16x16x32_bf16(a1, bq, z, 0, 0, 0);

        float e0[4], e1[4];
        #pragma unroll
        for (int r = 0; r < 4; ++r) {
            e0[r] = __builtin_amdgcn_exp2f(s0[r]);   // native v_exp_f32
            e1[r] = __builtin_amdgcn_exp2f(s1[r]);
            esum += e0[r] + e1[r];
        }

        uint2 pk0, pk1;
        pk0.x = pack2(e0[0], e0[1]); pk0.y = pack2(e0[2], e0[3]);
        pk1.x = pack2(e1[0], e1[1]); pk1.y = pack2(e1[2], e1[3]);
        *(uint2*)&P[m16 * PSTRD + 2 * g]     = pk0;   // keys 4g..4g+3
        *(uint2*)&P[m16 * PSTRD + 8 + 2 * g] = pk1;   // keys 16+4g..19+4g

        const short8 bp  = *(const short8*)&PS[m16 * 40 + g * 8];
        const short8 av0 = *(const short8*)(vbase + (size_t)m16 * 480 + kc * 32 + g * 8);
        const short8 av1 = *(const short8*)(vbase + (size_t)(16 + m16) * 480 + kc * 32 + g * 8);
        o0 = __builtin_amdgcn_mfma_f32_16x16x32_bf16(av0, bp, o0, 0, 0, 0);
        o1 = __builtin_amdgcn_mfma_f32_16x16x32_bf16(av1, bp, o1, 0, 0, 0);
    }

    float lsum = esum;
    lsum += __shfl_xor(lsum, 16, 64);
    lsum += __shfl_xor(lsum, 32, 64);
    const float linv = 1.0f / lsum;

    unsigned short* ob = out + ((size_t)(l * 384 + qrow0 + m16)) * 128 + h * 32;
    *(ushort4*)(ob + g * 4) = make_ushort4(
        f2bf(o0[0] * linv), f2bf(o0[1] * linv), f2bf(o0[2] * linv), f2bf(o0[3] * linv));
    *(ushort4*)(ob + 16 + g * 4) = make_ushort4(
        f2bf(o1[0] * linv), f2bf(o1[1] * linv), f2bf(o1[2] * linv), f2bf(o1[3] * linv));
}

// ---------------------------------------------------------------------------
// proj: mean over 6 views (bf16) -> @ Wp (MFMA) -> + bp + skip.
// 256 blocks x 256 thr: block = 16 rows; wave = 16 rows x 32 out-cols.
// ---------------------------------------------------------------------------
__global__ __launch_bounds__(256)
void proj_kernel(const unsigned short* __restrict__ attnb,
                 const unsigned short* __restrict__ Wpt,
                 const float* __restrict__ bp,
                 const float* __restrict__ skip,
                 float* __restrict__ out)
{
    const int t    = threadIdx.x;
    const int wv   = t >> 6;        // out-quarter
    const int lane = t & 63;
    const int m16  = lane & 15;
    const int g    = lane >> 4;

    const int row  = blockIdx.x * 16 + m16;
    const int l    = row >> 6;
    const int qrem = row & 63;

    short8 xf[4];
    #pragma unroll
    for (int kt = 0; kt < 4; ++kt) {
        float m[8] = {0,0,0,0,0,0,0,0};
        #pragma unroll
        for (int n = 0; n < 6; ++n) {
            const short8 vv = *(const short8*)(
                attnb + ((size_t)(l * 384 + n * 64 + qrem)) * 128 + kt * 32 + g * 8);
            #pragma unroll
            for (int jj = 0; jj < 8; ++jj)
                m[jj] += bf2f((unsigned short)vv[jj]);
        }
        short8 pk;
        #pragma unroll
        for (int jj = 0; jj < 8; ++jj) pk[jj] = (short)f2bf(m[jj] * (1.0f / 6.0f));
        xf[kt] = pk;
    }

    f32x4 acc[2] = {{0,0,0,0},{0,0,0,0}};
    #pragma unroll
    for (int kt = 0; kt < 4; ++kt) {
        #pragma unroll
        for (int ot = 0; ot < 2; ++ot) {
            const short8 aw = *(const short8*)&Wpt[
                (size_t)((wv * 2 + ot) * 16 + m16) * 128 + kt * 32 + g * 8];
            acc[ot] = __builtin_amdgcn_mfma_f32_16x16x32_bf16(aw, xf[kt], acc[ot], 0, 0, 0);
        }
    }

    #pragma unroll
    for (int ot = 0; ot < 2; ++ot) {
        const int ob = (wv * 2 + ot) * 16 + g * 4;
        const float4 bb = *(const float4*)&bp[ob];
        const float4 sk = *(const float4*)&skip[(size_t)row * D + ob];
        float4 r;
        r.x = acc[ot][0] + bb.x + sk.x;
        r.y = acc[ot][1] + bb.y + sk.y;
        r.z = acc[ot][2] + bb.z + sk.z;
        r.w = acc[ot][3] + bb.w + sk.w;
        *(float4*)&out[(size_t)row * D + ob] = r;
    }
}

// ---------------------------------------------------------------------------
extern "C" void kernel_launch(void* const* d_in, const int* in_sizes, int n_in,
                              void* d_out, int out_size, void* d_ws, size_t ws_size,
                              hipStream_t stream)
{
    const float* q          = (const float*)d_in[0];
    const float* k          = (const float*)d_in[1];
    const float* v          = (const float*)d_in[2];
    const float* skip       = (const float*)d_in[3];
    const float* attn_scale = (const float*)d_in[4];
    const float* lnq_g      = (const float*)d_in[5];
    const float* lnq_b      = (const float*)d_in[6];
    const float* Wq         = (const float*)d_in[7];
    const float* bq         = (const float*)d_in[8];
    const float* lnk_g      = (const float*)d_in[9];
    const float* lnk_b      = (const float*)d_in[10];
    const float* Wk         = (const float*)d_in[11];
    const float* bk         = (const float*)d_in[12];
    const float* lnv_g      = (const float*)d_in[13];
    const float* lnv_b      = (const float*)d_in[14];
    const float* Wv         = (const float*)d_in[15];
    const float* bv         = (const float*)d_in[16];
    const float* Wp         = (const float*)d_in[17];
    const float* bp         = (const float*)d_in[18];

    float* out = (float*)d_out;
    char*  wsb = (char*)d_ws;

    // ws layout (bytes)
    unsigned short* qbuf  = (unsigned short*)(wsb);              //  6,291,456
    unsigned short* kbuf  = (unsigned short*)(wsb + 6291456);    //  7,864,320
    unsigned short* vtb   = (unsigned short*)(wsb + 14155776);   //  7,864,320
    unsigned short* Wt    = (unsigned short*)(wsb + 22020096);   //     98,304
    unsigned short* Wpt   = (unsigned short*)(wsb + 22118400);   //     32,768
    float*          c1    = (float*)        (wsb + 22151168);    //      1,536
    float*          c2    = (float*)        (wsb + 22152704);    //      1,536
    unsigned short* attnb = (unsigned short*)(wsb + 22154240);   //  6,291,456

    wprep_kernel<<<512, 64, 0, stream>>>(Wq, Wk, Wv, Wp,
                                         lnq_g, lnq_b, bq,
                                         lnk_g, lnk_b, bk,
                                         lnv_g, lnv_b, bv,
                                         (unsigned*)Wt, (unsigned*)Wpt, c1, c2);

    ln_fused_kernel<<<1344, 256, 0, stream>>>(q, k, v, Wt, c1, c2,
                                              qbuf, kbuf, vtb, attn_scale);

    dim3 agrid(64, 4, 4);
    attn_kernel<<<agrid, 384, 0, stream>>>(qbuf, kbuf, vtb, attnb);

    proj_kernel<<<256, 256, 0, stream>>>(attnb, Wpt, bp, skip, out);
}

// Round 8
// 166.375 us; speedup vs baseline: 3.7292x; 1.1349x over previous
//
#include <hip/hip_runtime.h>

#define D 128
#define LN_EPS 1e-5f
#define PSTRD 20    // P row stride in dwords (16B-aligned)
#define WSTR 136    // Wt LDS row stride in shorts (272B = 17x16B: aligned, bank-min)

typedef __attribute__((ext_vector_type(8))) short short8;
typedef __attribute__((ext_vector_type(4))) float f32x4;

static __device__ __forceinline__ unsigned short f2bf(float f) {
    union { float f; unsigned u; } v; v.f = f;
    unsigned r = v.u + 0x7fffu + ((v.u >> 16) & 1u);   // RTNE
    return (unsigned short)(r >> 16);
}
static __device__ __forceinline__ unsigned pack2(float a, float b) {
    return (unsigned)f2bf(a) | ((unsigned)f2bf(b) << 16);
}
static __device__ __forceinline__ float bf2f(unsigned short u) {
    union { unsigned u; float f; } v; v.u = ((unsigned)u) << 16; return v.f;
}

// ---------------------------------------------------------------------------
// W prep: Wt = diag(g)W bf16 [out][in], c1 = g^T W, c2 = beta^T W + bias;
// Wpt = bf16 Wp^T.
// ---------------------------------------------------------------------------
__global__ __launch_bounds__(64)
void wprep_kernel(const float* __restrict__ Wq, const float* __restrict__ Wk,
                  const float* __restrict__ Wv, const float* __restrict__ Wp,
                  const float* __restrict__ gq, const float* __restrict__ betaq,
                  const float* __restrict__ biasq,
                  const float* __restrict__ gk, const float* __restrict__ betak,
                  const float* __restrict__ biask,
                  const float* __restrict__ gv, const float* __restrict__ betav,
                  const float* __restrict__ biasv,
                  unsigned* __restrict__ Wt, unsigned* __restrict__ Wpt,
                  float* __restrict__ c1, float* __restrict__ c2)
{
    const int id = blockIdx.x;
    const int w  = id >> 7;
    const int o  = id & 127;
    const int t  = threadIdx.x;
    if (w < 3) {
        const float* W  = (w == 0) ? Wq : (w == 1) ? Wk : Wv;
        const float* gg = (w == 0) ? gq : (w == 1) ? gk : gv;
        const float* bb = (w == 0) ? betaq : (w == 1) ? betak : betav;
        const float* bi = (w == 0) ? biasq : (w == 1) ? biask : biasv;
        const float w0 = W[(2 * t) * 128 + o];
        const float w1 = W[(2 * t + 1) * 128 + o];
        const float g0 = gg[2 * t], g1 = gg[2 * t + 1];
        const float b0 = bb[2 * t], b1 = bb[2 * t + 1];
        Wt[((size_t)w * 128 + o) * 64 + t] = pack2(g0 * w0, g1 * w1);
        float s1 = g0 * w0 + g1 * w1;
        float s2 = b0 * w0 + b1 * w1;
        #pragma unroll
        for (int off = 32; off > 0; off >>= 1) {
            s1 += __shfl_down(s1, off, 64);
            s2 += __shfl_down(s2, off, 64);
        }
        if (t == 0) { c1[w * 128 + o] = s1; c2[w * 128 + o] = s2 + bi[o]; }
    } else {
        Wpt[(size_t)o * 64 + t] = pack2(Wp[(2 * t) * 128 + o], Wp[(2 * t + 1) * 128 + o]);
    }
}

// ---------------------------------------------------------------------------
// LN+Linear body. Wt staged in LDS by caller; A-frags via ds_read_b128.
// Stats via X·1 and diag(X·X^T) MFMAs.
// NOTE: the smu/ssq exchange REQUIRES the __syncthreads(): the store is
// predicated and same-address as the load -> without a barrier LLVM can
// store-forward/hoist per-thread (R7 NaN failure).
// MODE 0: bf16 row-major. MODE 1: +scale (q). MODE 2: V^T scatter.
// ---------------------------------------------------------------------------
template<int PERL, int W1W2, int W2D, int MODE>
static __device__ __forceinline__
void ln_body(const float* __restrict__ in,
             const unsigned short* __restrict__ wlds,   // LDS, [128][WSTR]
             const float* __restrict__ c1, const float* __restrict__ c2,
             unsigned short* __restrict__ out,
             float scale, int rowbase, int t,
             float (*smu)[16], float (*ssq)[16])
{
    const int wv   = t >> 6;
    const int lane = t & 63;
    const int m16  = lane & 15;
    const int g    = lane >> 4;
    const int row  = rowbase + wv * 16 + m16;

    const int l   = row / PERL, j = row - l * PERL;
    const int n   = j / W1W2, rem = j - n * W1W2;
    const int w1  = rem / W2D, w2 = rem - w1 * W2D;
    const int X   = l >> 3, Y = l & 7;
    const float* xrow = in + ((size_t)(((n * 8 + X) * 8 + Y) * 8 + w1) * W2D + w2) * D;

    short8 xf[4];
    #pragma unroll
    for (int kt = 0; kt < 4; ++kt) {
        const float4 a = *(const float4*)(xrow + kt * 32 + g * 8);
        const float4 b = *(const float4*)(xrow + kt * 32 + g * 8 + 4);
        short8 vv;
        vv[0] = (short)f2bf(a.x); vv[1] = (short)f2bf(a.y);
        vv[2] = (short)f2bf(a.z); vv[3] = (short)f2bf(a.w);
        vv[4] = (short)f2bf(b.x); vv[5] = (short)f2bf(b.y);
        vv[6] = (short)f2bf(b.z); vv[7] = (short)f2bf(b.w);
        xf[kt] = vv;
    }

    short8 ones;
    #pragma unroll
    for (int jj = 0; jj < 8; ++jj) ones[jj] = (short)0x3F80;
    f32x4 sums = {0.f, 0.f, 0.f, 0.f}, gram = {0.f, 0.f, 0.f, 0.f};
    #pragma unroll
    for (int kt = 0; kt < 4; ++kt) {
        sums = __builtin_amdgcn_mfma_f32_16x16x32_bf16(xf[kt], ones, sums, 0, 0, 0);
        gram = __builtin_amdgcn_mfma_f32_16x16x32_bf16(xf[kt], xf[kt], gram, 0, 0, 0);
    }
    if (g == (m16 >> 2)) {
        smu[wv][m16] = sums[m16 & 3];
        ssq[wv][m16] = gram[m16 & 3];
    }
    __syncthreads();   // REQUIRED (see note above)
    const float mu   = smu[wv][m16] * (1.0f / 128.0f);
    const float msq  = ssq[wv][m16] * (1.0f / 128.0f);
    const float rstd = rsqrtf(msq - mu * mu + LN_EPS);
    const float rmu  = rstd * mu;

    f32x4 acc[8] = {{0,0,0,0},{0,0,0,0},{0,0,0,0},{0,0,0,0},
                    {0,0,0,0},{0,0,0,0},{0,0,0,0},{0,0,0,0}};
    #pragma unroll
    for (int kt = 0; kt < 4; ++kt) {
        #pragma unroll
        for (int ot = 0; ot < 8; ++ot) {
            const short8 aw = *(const short8*)&wlds[
                (ot * 16 + m16) * WSTR + kt * 32 + g * 8];
            acc[ot] = __builtin_amdgcn_mfma_f32_16x16x32_bf16(aw, xf[kt], acc[ot], 0, 0, 0);
        }
    }

    #pragma unroll
    for (int ot = 0; ot < 8; ++ot) {
        const int ob = ot * 16 + g * 4;
        const float4 cc1 = *(const float4*)&c1[ob];
        const float4 cc2 = *(const float4*)&c2[ob];
        float v0 = rstd * acc[ot][0] - rmu * cc1.x + cc2.x;
        float v1 = rstd * acc[ot][1] - rmu * cc1.y + cc2.y;
        float v2 = rstd * acc[ot][2] - rmu * cc1.z + cc2.z;
        float v3 = rstd * acc[ot][3] - rmu * cc1.w + cc2.w;
        if (MODE == 1) { v0 *= scale; v1 *= scale; v2 *= scale; v3 *= scale; }
        if (MODE == 2) {
            // transposed scatter: vtb[((l*4 + d>>5)*32 + (d&31))*480 + key]
            const float vals[4] = {v0, v1, v2, v3};
            #pragma unroll
            for (int c = 0; c < 4; ++c) {
                const int d = ob + c;
                out[((size_t)((l * 4 + (d >> 5)) * 32 + (d & 31))) * 480 + j] = f2bf(vals[c]);
            }
        } else {
            *(ushort4*)&out[(size_t)row * D + ob] =
                make_ushort4(f2bf(v0), f2bf(v1), f2bf(v2), f2bf(v3));
        }
    }
}

// Fused q/k/v LN+Linear. blocks [0,384): q  [384,864): k  [864,1344): v.
// Stages the branch's 32KB Wt into LDS (padded stride) before the GEMM.
__global__ __launch_bounds__(256, 4)
void ln_fused_kernel(const float* __restrict__ q, const float* __restrict__ k,
                     const float* __restrict__ v,
                     const unsigned short* __restrict__ Wt,
                     const float* __restrict__ c1, const float* __restrict__ c2,
                     unsigned short* __restrict__ qbuf,
                     unsigned short* __restrict__ kbuf,
                     unsigned short* __restrict__ vtb,
                     const float* __restrict__ scale_p)
{
    __shared__ __align__(16) unsigned short wlds[128 * WSTR];  // 34,816 B
    __shared__ float smu[4][16];
    __shared__ float ssq[4][16];

    const int bid = blockIdx.x;
    const int t   = threadIdx.x;

    const unsigned short* Wsrc =
        (bid < 384) ? Wt : (bid < 864) ? (Wt + 16384) : (Wt + 32768);

    // stage 32KB Wt -> LDS, coalesced uint4, padded row stride
    {
        const uint4* ws = (const uint4*)Wsrc;     // 2048 x 16B
        #pragma unroll
        for (int i = 0; i < 8; ++i) {
            const int idx = i * 256 + t;
            const int r = idx >> 4, s = idx & 15;
            *(uint4*)&wlds[r * WSTR + s * 8] = ws[idx];
        }
    }
    __syncthreads();

    if (bid < 384) {
        // fold attn_scale * dh^-0.5 * log2(e) into q (softmax via exp2)
        const float s = scale_p[0] * 0.17677669529663687f * 1.4426950408889634f;
        ln_body<384, 64, 8, 1>(q, wlds, c1, c2, qbuf, s, bid * 64, t, smu, ssq);
    } else if (bid < 864) {
        ln_body<480, 80, 10, 0>(k, wlds, c1 + 128, c2 + 128, kbuf,
                                1.0f, (bid - 384) * 64, t, smu, ssq);
    } else {
        ln_body<480, 80, 10, 2>(v, wlds, c1 + 256, c2 + 256, vtb,
                                1.0f, (bid - 864) * 64, t, smu, ssq);
    }
}

// ---------------------------------------------------------------------------
// Flash attention (unchanged from R6): zero staging, barrier-free, no-max
// softmax with exp2 (log2e folded into q). Grid (64 l, 4 h, 4 qz) x 384.
// ---------------------------------------------------------------------------
__global__ __launch_bounds__(384)
void attn_kernel(const unsigned short* __restrict__ qb,
                 const unsigned short* __restrict__ kb,
                 const unsigned short* __restrict__ vtb,
                 unsigned short* __restrict__ out)
{
    __shared__ __align__(16) unsigned Pall[6 * 16 * PSTRD];  // 7680 B

    const int l    = blockIdx.x;
    const int h    = blockIdx.y;
    const int qz   = blockIdx.z;
    const int t    = threadIdx.x;
    const int wv   = t >> 6;
    const int lane = t & 63;
    const int m16  = lane & 15;
    const int g    = lane >> 4;

    unsigned* P = &Pall[wv * 16 * PSTRD];
    const unsigned short* PS = (const unsigned short*)P;     // stride 40 shorts

    const int qrow0 = qz * 96 + wv * 16;
    const short8 bq = *(const short8*)(
        qb + ((size_t)(l * 384 + qrow0 + m16)) * 128 + h * 32 + g * 8);

    const unsigned short* kbase = kb + ((size_t)l * 480) * 128 + h * 32;
    const unsigned short* vbase = vtb + ((size_t)(l * 4 + h) * 32) * 480;

    f32x4 o0 = {0.f, 0.f, 0.f, 0.f};
    f32x4 o1 = {0.f, 0.f, 0.f, 0.f};
    float esum = 0.f;

    #pragma unroll 3
    for (int kc = 0; kc < 15; ++kc) {
        const short8 a0 = *(const short8*)(kbase + (size_t)(kc * 32 + m16) * 128 + g * 8);
        const short8 a1 = *(const short8*)(kbase + (size_t)(kc * 32 + 16 + m16) * 128 + g * 8);
        const f32x4 z = {0.f, 0.f, 0.f, 0.f};
        const f32x4 s0 = __builtin_amdgcn_mfma_f32_16x16x32_bf16(a0, bq, z, 0, 0, 0);
        const f32x4 s1 = __builtin_amdgcn_mfma_f32_16x16x32_bf16(a1, bq, z, 0, 0, 0);

        float e0[4], e1[4];
        #pragma unroll
        for (int r = 0; r < 4; ++r) {
            e0[r] = __builtin_amdgcn_exp2f(s0[r]);   // native v_exp_f32
            e1[r] = __builtin_amdgcn_exp2f(s1[r]);
            esum += e0[r] + e1[r];
        }

        uint2 pk0, pk1;
        pk0.x = pack2(e0[0], e0[1]); pk0.y = pack2(e0[2], e0[3]);
        pk1.x = pack2(e1[0], e1[1]); pk1.y = pack2(e1[2], e1[3]);
        *(uint2*)&P[m16 * PSTRD + 2 * g]     = pk0;   // keys 4g..4g+3
        *(uint2*)&P[m16 * PSTRD + 8 + 2 * g] = pk1;   // keys 16+4g..19+4g

        const short8 bp  = *(const short8*)&PS[m16 * 40 + g * 8];
        const short8 av0 = *(const short8*)(vbase + (size_t)m16 * 480 + kc * 32 + g * 8);
        const short8 av1 = *(const short8*)(vbase + (size_t)(16 + m16) * 480 + kc * 32 + g * 8);
        o0 = __builtin_amdgcn_mfma_f32_16x16x32_bf16(av0, bp, o0, 0, 0, 0);
        o1 = __builtin_amdgcn_mfma_f32_16x16x32_bf16(av1, bp, o1, 0, 0, 0);
    }

    float lsum = esum;
    lsum += __shfl_xor(lsum, 16, 64);
    lsum += __shfl_xor(lsum, 32, 64);
    const float linv = 1.0f / lsum;

    unsigned short* ob = out + ((size_t)(l * 384 + qrow0 + m16)) * 128 + h * 32;
    *(ushort4*)(ob + g * 4) = make_ushort4(
        f2bf(o0[0] * linv), f2bf(o0[1] * linv), f2bf(o0[2] * linv), f2bf(o0[3] * linv));
    *(ushort4*)(ob + 16 + g * 4) = make_ushort4(
        f2bf(o1[0] * linv), f2bf(o1[1] * linv), f2bf(o1[2] * linv), f2bf(o1[3] * linv));
}

// ---------------------------------------------------------------------------
// proj (unchanged from R6): mean over 6 views (bf16) -> @ Wp (MFMA) -> + bp
// + skip. 256 blocks x 256 thr.
// ---------------------------------------------------------------------------
__global__ __launch_bounds__(256)
void proj_kernel(const unsigned short* __restrict__ attnb,
                 const unsigned short* __restrict__ Wpt,
                 const float* __restrict__ bp,
                 const float* __restrict__ skip,
                 float* __restrict__ out)
{
    const int t    = threadIdx.x;
    const int wv   = t >> 6;        // out-quarter
    const int lane = t & 63;
    const int m16  = lane & 15;
    const int g    = lane >> 4;

    const int row  = blockIdx.x * 16 + m16;
    const int l    = row >> 6;
    const int qrem = row & 63;

    short8 xf[4];
    #pragma unroll
    for (int kt = 0; kt < 4; ++kt) {
        float m[8] = {0,0,0,0,0,0,0,0};
        #pragma unroll
        for (int n = 0; n < 6; ++n) {
            const short8 vv = *(const short8*)(
                attnb + ((size_t)(l * 384 + n * 64 + qrem)) * 128 + kt * 32 + g * 8);
            #pragma unroll
            for (int jj = 0; jj < 8; ++jj)
                m[jj] += bf2f((unsigned short)vv[jj]);
        }
        short8 pk;
        #pragma unroll
        for (int jj = 0; jj < 8; ++jj) pk[jj] = (short)f2bf(m[jj] * (1.0f / 6.0f));
        xf[kt] = pk;
    }

    f32x4 acc[2] = {{0,0,0,0},{0,0,0,0}};
    #pragma unroll
    for (int kt = 0; kt < 4; ++kt) {
        #pragma unroll
        for (int ot = 0; ot < 2; ++ot) {
            const short8 aw = *(const short8*)&Wpt[
                (size_t)((wv * 2 + ot) * 16 + m16) * 128 + kt * 32 + g * 8];
            acc[ot] = __builtin_amdgcn_mfma_f32_16x16x32_bf16(aw, xf[kt], acc[ot], 0, 0, 0);
        }
    }

    #pragma unroll
    for (int ot = 0; ot < 2; ++ot) {
        const int ob = (wv * 2 + ot) * 16 + g * 4;
        const float4 bb = *(const float4*)&bp[ob];
        const float4 sk = *(const float4*)&skip[(size_t)row * D + ob];
        float4 r;
        r.x = acc[ot][0] + bb.x + sk.x;
        r.y = acc[ot][1] + bb.y + sk.y;
        r.z = acc[ot][2] + bb.z + sk.z;
        r.w = acc[ot][3] + bb.w + sk.w;
        *(float4*)&out[(size_t)row * D + ob] = r;
    }
}

// ---------------------------------------------------------------------------
extern "C" void kernel_launch(void* const* d_in, const int* in_sizes, int n_in,
                              void* d_out, int out_size, void* d_ws, size_t ws_size,
                              hipStream_t stream)
{
    const float* q          = (const float*)d_in[0];
    const float* k          = (const float*)d_in[1];
    const float* v          = (const float*)d_in[2];
    const float* skip       = (const float*)d_in[3];
    const float* attn_scale = (const float*)d_in[4];
    const float* lnq_g      = (const float*)d_in[5];
    const float* lnq_b      = (const float*)d_in[6];
    const float* Wq         = (const float*)d_in[7];
    const float* bq         = (const float*)d_in[8];
    const float* lnk_g      = (const float*)d_in[9];
    const float* lnk_b      = (const float*)d_in[10];
    const float* Wk         = (const float*)d_in[11];
    const float* bk         = (const float*)d_in[12];
    const float* lnv_g      = (const float*)d_in[13];
    const float* lnv_b      = (const float*)d_in[14];
    const float* Wv         = (const float*)d_in[15];
    const float* bv         = (const float*)d_in[16];
    const float* Wp         = (const float*)d_in[17];
    const float* bp         = (const float*)d_in[18];

    float* out = (float*)d_out;
    char*  wsb = (char*)d_ws;

    // ws layout (bytes)
    unsigned short* qbuf  = (unsigned short*)(wsb);              //  6,291,456
    unsigned short* kbuf  = (unsigned short*)(wsb + 6291456);    //  7,864,320
    unsigned short* vtb   = (unsigned short*)(wsb + 14155776);   //  7,864,320
    unsigned short* Wt    = (unsigned short*)(wsb + 22020096);   //     98,304
    unsigned short* Wpt   = (unsigned short*)(wsb + 22118400);   //     32,768
    float*          c1    = (float*)        (wsb + 22151168);    //      1,536
    float*          c2    = (float*)        (wsb + 22152704);    //      1,536
    unsigned short* attnb = (unsigned short*)(wsb + 22154240);   //  6,291,456

    wprep_kernel<<<512, 64, 0, stream>>>(Wq, Wk, Wv, Wp,
                                         lnq_g, lnq_b, bq,
                                         lnk_g, lnk_b, bk,
                                         lnv_g, lnv_b, bv,
                                         (unsigned*)Wt, (unsigned*)Wpt, c1, c2);

    ln_fused_kernel<<<1344, 256, 0, stream>>>(q, k, v, Wt, c1, c2,
                                              qbuf, kbuf, vtb, attn_scale);

    dim3 agrid(64, 4, 4);
    attn_kernel<<<agrid, 384, 0, stream>>>(qbuf, kbuf, vtb, attnb);

    proj_kernel<<<256, 256, 0, stream>>>(attnb, Wpt, bp, skip, out);
}